// Round 9
// baseline (1120.671 us; speedup 1.0000x reference)
//
#include <hip/hip_runtime.h>
#include <hip/hip_bf16.h>
#include <math.h>

#define B_  64
#define A_  26
#define L_  384
#define D_  512
#define K_  18
#define LP1 385   // L_ + 1
#define VS  384   // Vsto row stride; Vsto[i-1][j-1] = V[i][j]

typedef __attribute__((ext_vector_type(8))) short bf16x8;   // 8 bf16 = 4 VGPRs
typedef __attribute__((ext_vector_type(4))) float f32x4;
typedef unsigned short ushort_t;
typedef unsigned int uint_t;

// RNE f32 -> bf16 bits
__device__ __forceinline__ ushort_t f2bf(float v) {
    uint_t u = __float_as_uint(v);
    uint_t r = (u + 0x7FFFu + ((u >> 16) & 1u)) >> 16;
    return (ushort_t)r;
}

// DPP lane shifts (gfx9-family wave shifts, VALU-speed; bound_ctrl -> 0 fill)
__device__ __forceinline__ float dpp_up1(float x) {   // lane i <- lane i-1; lane0 <- 0
    return __int_as_float(__builtin_amdgcn_update_dpp(
        0, __float_as_int(x), 0x138, 0xF, 0xF, true));  // WAVE_SHR1
}
__device__ __forceinline__ float dpp_down1(float x) { // lane i <- lane i+1; lane63 <- 0
    return __int_as_float(__builtin_amdgcn_update_dpp(
        0, __float_as_int(x), 0x130, 0xF, 0xF, true));  // WAVE_SHL1
}

// ---------------- conv weight transpose: (D,A,K) -> (A*K, D) ----------------
__global__ void transpose_w_kernel(const float* __restrict__ w, float* __restrict__ wt) {
    int o = blockIdx.x * blockDim.x + threadIdx.x;   // o = r*D + d
    int total = A_ * K_ * D_;
    if (o >= total) return;
    int d = o % D_;
    int r = o / D_;                                   // r = a*K + k
    wt[o] = w[(size_t)d * (A_ * K_) + r];
}

// ---------------- conv1d -> e_hi/e_lo (B, L, D) bf16 split ----------------
__global__ __launch_bounds__(512) void conv_kernel(const float* __restrict__ x,     // (B, A, L)
                                                   const float* __restrict__ wt,    // (A*K, D)
                                                   const float* __restrict__ bias,  // (D,)
                                                   ushort_t* __restrict__ ehi,      // (B, L, D) bf16
                                                   ushort_t* __restrict__ elo) {    // (B, L, D) bf16
    const int TL = 32;
    const int XW = TL + K_ - 1;     // 49
    int l0 = blockIdx.x * TL;
    int b  = blockIdx.y;
    int d  = threadIdx.x;           // 512 threads, one per output channel
    __shared__ float xs[A_][XW];
    for (int idx = threadIdx.x; idx < A_ * XW; idx += 512) {
        int a = idx / XW, p = idx % XW;
        int g = l0 - (K_ - 1) / 2 + p;  // l0 - 8 + p
        xs[a][p] = (g >= 0 && g < L_) ? x[((size_t)b * A_ + a) * L_ + g] : 0.0f;
    }
    __syncthreads();
    float acc[TL];
#pragma unroll
    for (int l = 0; l < TL; ++l) acc[l] = 0.0f;
#pragma unroll 1
    for (int a = 0; a < A_; ++a) {
        float xr[XW];
#pragma unroll
        for (int p = 0; p < XW; ++p) xr[p] = xs[a][p];
        const float* wrow = wt + (size_t)(a * K_) * D_ + d;
#pragma unroll
        for (int k = 0; k < K_; ++k) {
            float w = wrow[(size_t)k * D_];
#pragma unroll
            for (int l = 0; l < TL; ++l)
                acc[l] = fmaf(xr[k + l], w, acc[l]);
        }
    }
    float bv = bias[d];
#pragma unroll
    for (int l = 0; l < TL; ++l) {
        float v = acc[l] + bv;
        ushort_t h = f2bf(v);
        float hf = __uint_as_float(((uint_t)h) << 16);
        ushort_t lo = f2bf(v - hf);
        size_t idx = ((size_t)b * L_ + (l0 + l)) * D_ + d;
        ehi[idx] = h;
        elo[idx] = lo;
    }
}

// ---------------- sim = E_b · E_0^T via split-bf16 MFMA ----------------
__global__ __launch_bounds__(256) void sim_kernel(const ushort_t* __restrict__ ehi,
                                                  const ushort_t* __restrict__ elo,
                                                  float* __restrict__ sim) {
    int b = blockIdx.z;
    int w = threadIdx.x >> 6;
    int lane = threadIdx.x & 63;
    int l0 = blockIdx.y * 64 + 32 * (w >> 1);
    int m0 = blockIdx.x * 64 + 32 * (w & 1);
    int r = lane & 15, g = lane >> 4;
    size_t rowA = ((size_t)b * L_ + l0 + r) * D_ + g * 8;
    size_t rowB = ((size_t)m0 + r) * D_ + g * 8;      // batch 0
    const ushort_t* pah = ehi + rowA;
    const ushort_t* pal = elo + rowA;
    const ushort_t* pbh = ehi + rowB;
    const ushort_t* pbl = elo + rowB;
    f32x4 acc00 = {0.f, 0.f, 0.f, 0.f}, acc01 = acc00, acc10 = acc00, acc11 = acc00;
#pragma unroll 2
    for (int ks = 0; ks < 16; ++ks) {
        int off = ks * 32;
        bf16x8 Ah0 = *(const bf16x8*)(pah + off);
        bf16x8 Ah1 = *(const bf16x8*)(pah + 16 * D_ + off);
        bf16x8 Al0 = *(const bf16x8*)(pal + off);
        bf16x8 Al1 = *(const bf16x8*)(pal + 16 * D_ + off);
        bf16x8 Bh0 = *(const bf16x8*)(pbh + off);
        bf16x8 Bh1 = *(const bf16x8*)(pbh + 16 * D_ + off);
        bf16x8 Bl0 = *(const bf16x8*)(pbl + off);
        bf16x8 Bl1 = *(const bf16x8*)(pbl + 16 * D_ + off);
        acc00 = __builtin_amdgcn_mfma_f32_16x16x32_bf16(Ah0, Bh0, acc00, 0, 0, 0);
        acc00 = __builtin_amdgcn_mfma_f32_16x16x32_bf16(Ah0, Bl0, acc00, 0, 0, 0);
        acc00 = __builtin_amdgcn_mfma_f32_16x16x32_bf16(Al0, Bh0, acc00, 0, 0, 0);
        acc01 = __builtin_amdgcn_mfma_f32_16x16x32_bf16(Ah0, Bh1, acc01, 0, 0, 0);
        acc01 = __builtin_amdgcn_mfma_f32_16x16x32_bf16(Ah0, Bl1, acc01, 0, 0, 0);
        acc01 = __builtin_amdgcn_mfma_f32_16x16x32_bf16(Al0, Bh1, acc01, 0, 0, 0);
        acc10 = __builtin_amdgcn_mfma_f32_16x16x32_bf16(Ah1, Bh0, acc10, 0, 0, 0);
        acc10 = __builtin_amdgcn_mfma_f32_16x16x32_bf16(Ah1, Bl0, acc10, 0, 0, 0);
        acc10 = __builtin_amdgcn_mfma_f32_16x16x32_bf16(Al1, Bh0, acc10, 0, 0, 0);
        acc11 = __builtin_amdgcn_mfma_f32_16x16x32_bf16(Ah1, Bh1, acc11, 0, 0, 0);
        acc11 = __builtin_amdgcn_mfma_f32_16x16x32_bf16(Ah1, Bl1, acc11, 0, 0, 0);
        acc11 = __builtin_amdgcn_mfma_f32_16x16x32_bf16(Al1, Bh1, acc11, 0, 0, 0);
    }
    float* sp = sim + ((size_t)b * L_ + l0) * L_ + m0;
#pragma unroll
    for (int v = 0; v < 4; ++v) {
        int row = g * 4 + v;
        sp[(size_t)row * L_ + r]             = acc00[v];
        sp[(size_t)row * L_ + 16 + r]        = acc01[v];
        sp[(size_t)(16 + row) * L_ + r]      = acc10[v];
        sp[(size_t)(16 + row) * L_ + 16 + r] = acc11[v];
    }
}

// ---------------- NW forward: one wave/batch, 6 rows/lane, 4-col register tiles, depth-2 prefetch ----------------
// V[i,j] = sim[i-1,j-1] + smoothmax3(V[i-1,j-1], V[i-1,j], V[i,j-1])   (g=0, t=1)
__global__ __launch_bounds__(64, 1) void nw_fwd_kernel(const float* __restrict__ sim, float* __restrict__ V) {
    int b = blockIdx.x;
    int l = threadIdx.x;
    const float* sb = sim + (size_t)b * L_ * L_;
    float* Vb = V + (size_t)b * L_ * L_;             // Vsto layout
    const float* srow[6];
    float* vrow[6];
#pragma unroll
    for (int r = 0; r < 6; ++r) {
        srow[r] = sb + (size_t)(6 * l + r) * L_;
        vrow[r] = Vb + (size_t)(6 * l + r) * VS;
    }
    float vleft[6] = {0.f, 0.f, 0.f, 0.f, 0.f, 0.f};  // V[i, 0] = 0
    float bcarry[4] = {0.f, 0.f, 0.f, 0.f};           // row-5 V at this tile's cols
    float bprev = 0.f;                                // row-5 V at col c0-1
    float4 snA[6], snB[6];                            // depth-2 prefetch buffers
    {
        int cA = min(max(4 * (0 - l), 0), 380);
        int cB = min(max(4 * (1 - l), 0), 380);
#pragma unroll
        for (int r = 0; r < 6; ++r) {
            snA[r] = *(const float4*)(srow[r] + cA);
            snB[r] = *(const float4*)(srow[r] + cB);
        }
    }
#pragma unroll 1
    for (int T = 0; T < 159; ++T) {
        float sc[6][4];
#pragma unroll
        for (int r = 0; r < 6; ++r) {
            float4 t = snA[r];
            sc[r][0] = t.x; sc[r][1] = t.y; sc[r][2] = t.z; sc[r][3] = t.w;
            snA[r] = snB[r];
        }
        int cP = min(max(4 * (T + 2 - l), 0), 380);
#pragma unroll
        for (int r = 0; r < 6; ++r) snB[r] = *(const float4*)(srow[r] + cP);
        // cross-lane inputs (whole-wave, outside divergent region)
        float d0 = dpp_up1(bprev);                   // V[6l, c0]
        float uin[4];
#pragma unroll
        for (int q = 0; q < 4; ++q) uin[q] = dpp_up1(bcarry[q]);   // V[6l, c0+q+1]
        int c0 = 4 * (T - l);
        if (c0 >= 0 && c0 <= 380) {
            float vout[6][4];
#pragma unroll
            for (int q = 0; q < 4; ++q) {
                float dg = (q == 0) ? d0 : uin[q - 1];
                float up = uin[q];
#pragma unroll
                for (int r = 0; r < 6; ++r) {
                    float lf = vleft[r];
                    float mx = fmaxf(dg, fmaxf(up, lf));
                    float v = sc[r][q] + mx + __logf(__expf(dg - mx) + __expf(up - mx) + __expf(lf - mx));
                    dg = lf;                          // diag for row r+1
                    up = v;                           // up for row r+1
                    vleft[r] = v;
                    vout[r][q] = v;
                }
            }
            bprev = bcarry[3];
#pragma unroll
            for (int q = 0; q < 4; ++q) bcarry[q] = vout[5][q];
#pragma unroll
            for (int r = 0; r < 6; ++r) {
                float4 t;
                t.x = vout[r][0]; t.y = vout[r][1]; t.z = vout[r][2]; t.w = vout[r][3];
                *(float4*)(vrow[r] + c0) = t;
            }
        }
    }
}

// ---------------- NW backward: 3 passes x 2 rows/lane, depth-3 prefetch, LDS U/E boundary ----------------
// E[i,j] = [i==li && j==lj] + E[i+1,j+1]*exp(V[i,j]-U[i+1,j+1]) + E[i+1,j]*exp(V[i,j]-U[i+1,j])
//        + E[i,j+1]*exp(V[i,j]-U[i,j+1]),   U[i,j] = V[i,j] - sim0[i-1][j-1].
// Boundary row r0+129 (lane 63's neighbor) = previous pass lane-0 row: its E AND U
// pass through LDS (Eb/Ub), removing the per-lane V2/S2 global streams entirely.
// Pass 0's boundary is fully guarded by i2<L_ (zero-init safe).
__global__ __launch_bounds__(64, 1) void nw_bwd_kernel(const float* __restrict__ sim,
                                                       const float* __restrict__ V,
                                                       const int* __restrict__ shapes,
                                                       float* __restrict__ align_) {
    int b = blockIdx.x;
    int l = threadIdx.x;
    const float* sb = sim + (size_t)b * L_ * L_;
    const float* Vb = V + (size_t)b * L_ * L_;       // Vsto layout
    float* ab = align_ + (size_t)b * L_ * L_;
    int li = min(max(shapes[2 * b + 0], 0), L_);
    int lj = min(max(shapes[2 * b + 1], 0), L_);
    __shared__ float Eb[2][388];                     // [parity][j-1] = E[r0+129, j]
    __shared__ float Ub[2][388];                     // [parity][j-1] = U[r0+129, j]
    for (int k = l; k < 2 * 388; k += 64) { ((float*)Eb)[k] = 0.f; ((float*)Ub)[k] = 0.f; }
    bool L63 = (l == 63);
#pragma unroll 1
    for (int pass = 0; pass < 3; ++pass) {
        int r0 = 256 - 128 * pass;
        int i1 = r0 + 2 * l + 1, i2 = i1 + 1;
        const float* pV0 = Vb + (size_t)(r0 + 2 * l) * VS;       // V[i1, *]
        const float* pV1 = Vb + (size_t)(r0 + 2 * l + 1) * VS;   // V[i2, *]
        const float* pS0 = sb + (size_t)(r0 + 2 * l) * L_;       // sim0[i1-1][*]
        const float* pS1 = sb + (size_t)(r0 + 2 * l + 1) * L_;   // sim0[i2-1][*]
        float* pE0 = ab + (size_t)(i1 - 1) * L_;
        float* pE1 = ab + (size_t)(i2 - 1) * L_;
        const float* Ebr = Eb[pass & 1];
        float* Ebw = Eb[(pass & 1) ^ 1];
        const float* Ubr = Ub[pass & 1];
        float* Ubw = Ub[(pass & 1) ^ 1];
        float e0 = 0.f, e1 = 0.f, u0p = 0.f, u1p = 0.f;          // E/U[i*, j+1] carries
        float ecarry[4] = {0.f, 0.f, 0.f, 0.f};                  // E[i1, tile cols] (for lane l-1)
        float ucarry[4] = {0.f, 0.f, 0.f, 0.f};                  // U[i1, tile cols]
        float eprev_s = 0.f, uprev_s = 0.f;                      // E/U[i1, jhi+1] snapshots
        float eb_carry = 0.f, ub_carry = 0.f;                    // lane63 boundary carries
        float4 bV0[3], bV1[3], bS0[3], bS1[3];                   // depth-3 prefetch ring
#pragma unroll
        for (int s = 0; s < 3; ++s) {
            int cP = min(max(380 - 4 * (s - (63 - l)), 0), 380);
            bV0[s] = *(const float4*)(pV0 + cP);
            bV1[s] = *(const float4*)(pV1 + cP);
            bS0[s] = *(const float4*)(pS0 + cP);
            bS1[s] = *(const float4*)(pS1 + cP);
        }
#pragma unroll 1
        for (int T = 0; T < 159; ++T) {
            float V0q[4], V1q[4], S0q[4], S1q[4];
            { float4 t = bV0[0]; V0q[0]=t.x; V0q[1]=t.y; V0q[2]=t.z; V0q[3]=t.w; }
            { float4 t = bV1[0]; V1q[0]=t.x; V1q[1]=t.y; V1q[2]=t.z; V1q[3]=t.w; }
            { float4 t = bS0[0]; S0q[0]=t.x; S0q[1]=t.y; S0q[2]=t.z; S0q[3]=t.w; }
            { float4 t = bS1[0]; S1q[0]=t.x; S1q[1]=t.y; S1q[2]=t.z; S1q[3]=t.w; }
            bV0[0] = bV0[1]; bV0[1] = bV0[2];
            bV1[0] = bV1[1]; bV1[1] = bV1[2];
            bS0[0] = bS0[1]; bS0[1] = bS0[2];
            bS1[0] = bS1[1]; bS1[1] = bS1[2];
            int cP = min(max(380 - 4 * (T + 3 - (63 - l)), 0), 380);
            bV0[2] = *(const float4*)(pV0 + cP);
            bV1[2] = *(const float4*)(pV1 + cP);
            bS0[2] = *(const float4*)(pS0 + cP);
            bS1[2] = *(const float4*)(pS1 + cP);
            int c0 = 380 - 4 * (T - (63 - l));
            // cross-lane (whole-wave): lane l+1 covered these cols at T-1
            float enbtd3 = dpp_down1(eprev_s);       // E[i2+1, jhi+1]
            float unbtd3 = dpp_down1(uprev_s);       // U[i2+1, jhi+1]
            float enbc[4], unbc[4];
#pragma unroll
            for (int q = 0; q < 4; ++q) {
                enbc[q] = dpp_down1(ecarry[q]);      // E[i2+1, c0+1+q]
                unbc[q] = dpp_down1(ucarry[q]);      // U[i2+1, c0+1+q]
            }
            eprev_s = e0; uprev_s = u0p;             // snapshot AFTER dpps
            if (c0 >= 0 && c0 <= 380) {
                float ebq[4] = {0.f, 0.f, 0.f, 0.f};
                float ubq[4] = {0.f, 0.f, 0.f, 0.f};
                if (L63) {
                    float4 t = *(const float4*)&Ebr[c0];
                    ebq[0] = t.x; ebq[1] = t.y; ebq[2] = t.z; ebq[3] = t.w;
                    float4 u = *(const float4*)&Ubr[c0];
                    ubq[0] = u.x; ubq[1] = u.y; ubq[2] = u.z; ubq[3] = u.w;
                }
                float u0c[4], u1c[4];
#pragma unroll
                for (int q = 0; q < 4; ++q) {
                    u0c[q] = V0q[q] - S0q[q];        // U[i1, c0+1+q]
                    u1c[q] = V1q[q] - S1q[q];        // U[i2, c0+1+q]
                }
                float Eo0[4], Eo1[4];
#pragma unroll
                for (int qq = 0; qq < 4; ++qq) {
                    const int q = 3 - qq;            // descending cols
                    int j = c0 + 1 + q;
                    float enb   = L63 ? ebq[q] : enbc[q];
                    float unb   = L63 ? ubq[q] : unbc[q];
                    float enbtd = (q == 3) ? (L63 ? eb_carry : enbtd3)
                                           : (L63 ? ebq[q + 1] : enbc[q + 1]);
                    float unbtd = (q == 3) ? (L63 ? ub_carry : unbtd3)
                                           : (L63 ? ubq[q + 1] : unbc[q + 1]);
                    bool jlt = (j < L_), i2lt = (i2 < L_);
                    float wtd1 = (i2lt && jlt) ? __expf(V1q[q] - unbtd) : 0.f;
                    float wtu1 = i2lt ? __expf(V1q[q] - unb) : 0.f;
                    float wtl1 = jlt ? __expf(V1q[q] - u1p) : 0.f;
                    float wtd0 = jlt ? __expf(V0q[q] - u1p) : 0.f;
                    float wtu0 = __expf(V0q[q] - u1c[q]);
                    float wtl0 = jlt ? __expf(V0q[q] - u0p) : 0.f;
                    float ea1 = (i2 == li && j == lj) ? 1.f : 0.f;
                    ea1 += wtd1 * enbtd + wtu1 * enb + wtl1 * e1;
                    float ea0 = (i1 == li && j == lj) ? 1.f : 0.f;
                    ea0 += wtd0 * e1 + wtu0 * ea1 + wtl0 * e0;
                    e1 = ea1; e0 = ea0;
                    u1p = u1c[q]; u0p = u0c[q];
                    Eo1[q] = ea1; Eo0[q] = ea0;
                }
                eb_carry = ebq[0]; ub_carry = ubq[0];
#pragma unroll
                for (int q = 0; q < 4; ++q) { ecarry[q] = Eo0[q]; ucarry[q] = u0c[q]; }
                float4 t0, t1;
                t0.x = Eo0[0]; t0.y = Eo0[1]; t0.z = Eo0[2]; t0.w = Eo0[3];
                t1.x = Eo1[0]; t1.y = Eo1[1]; t1.z = Eo1[2]; t1.w = Eo1[3];
                *(float4*)(pE0 + c0) = t0;
                *(float4*)(pE1 + c0) = t1;
                if (l == 0) {                         // boundary E and U for next pass
                    *(float4*)&Ebw[c0] = t0;
                    float4 tu;
                    tu.x = u0c[0]; tu.y = u0c[1]; tu.z = u0c[2]; tu.w = u0c[3];
                    *(float4*)&Ubw[c0] = tu;
                }
            }
        }
    }
}

// ---------------- consensus[j,a] = (1/B) sum_n sum_i matrices[n,a,i]*align[n,i,j] ----------------
__global__ __launch_bounds__(256) void consensus_kernel(const float* __restrict__ x,      // (B,A,L)
                                                        const float* __restrict__ align_, // (B,L,L)
                                                        float* __restrict__ cons) {       // (L,A)
    int n  = blockIdx.y;
    int j0 = blockIdx.x * 64;
    __shared__ float ms[A_][L_];    // 39.9 KB: matrices[n] staged
    for (int idx = threadIdx.x; idx < A_ * L_; idx += 256)
        ((float*)ms)[idx] = x[(size_t)n * A_ * L_ + idx];
    __syncthreads();
    int jl = threadIdx.x & 63;
    int g  = threadIdx.x >> 6;      // 0..3
    int a0 = g * 7;                 // 0,7,14,21
    int na = (a0 + 7 <= A_) ? 7 : (A_ - a0);   // 7,7,7,5
    int j  = j0 + jl;
    float acc[7] = {0.f, 0.f, 0.f, 0.f, 0.f, 0.f, 0.f};
    const float* acol = align_ + (size_t)n * L_ * L_ + j;
    for (int i = 0; i < L_; ++i) {
        float al = acol[(size_t)i * L_];
#pragma unroll
        for (int t = 0; t < 7; ++t)
            if (t < na) acc[t] = fmaf(al, ms[a0 + t][i], acc[t]);
    }
    for (int t = 0; t < na; ++t)
        atomicAdd(&cons[(size_t)j * A_ + a0 + t], acc[t] * (1.0f / B_));
}

// ---------------- out[n,i,a] = sum_j cons[j,a] * align[n,i,j] ----------------
__global__ __launch_bounds__(256) void out_kernel(const float* __restrict__ align_,
                                                  const float* __restrict__ cons,
                                                  float* __restrict__ out) {
    int n  = blockIdx.y;
    int i0 = blockIdx.x * 32;
    __shared__ float cs[L_][A_];        // 40.0 KB
    __shared__ float as_[32][L_ + 1];   // 49.3 KB (pad: break 384-stride bank alias)
    for (int idx = threadIdx.x; idx < L_ * A_; idx += 256)
        ((float*)cs)[idx] = cons[idx];
    for (int idx = threadIdx.x; idx < 32 * L_; idx += 256) {
        int r = idx / L_, c = idx % L_;
        as_[r][c] = align_[((size_t)n * L_ + i0 + r) * L_ + c];
    }
    __syncthreads();
    for (int o = threadIdx.x; o < 32 * A_; o += 256) {
        int il = o / A_, a = o % A_;
        float s = 0.f;
        for (int jj = 0; jj < L_; ++jj)
            s = fmaf(as_[il][jj], cs[jj][a], s);
        out[((size_t)n * L_ + i0 + il) * A_ + a] = s;
    }
}

extern "C" void kernel_launch(void* const* d_in, const int* in_sizes, int n_in,
                              void* d_out, int out_size, void* d_ws, size_t ws_size,
                              hipStream_t stream) {
    const float* matrices = (const float*)d_in[0];   // (B,A,L) f32
    const int*   shapes   = (const int*)d_in[1];     // (B,2) i32
    const float* conv_w   = (const float*)d_in[2];   // (D,A,K) f32
    const float* conv_b   = (const float*)d_in[3];   // (D,) f32
    float* out = (float*)d_out;                      // (B,L,A) f32

    char* p = (char*)d_ws;
    ushort_t* ehi = (ushort_t*)p;  p += (size_t)B_ * L_ * D_ * 2;   // 25.2 MB bf16
    ushort_t* elo = (ushort_t*)p;  p += (size_t)B_ * L_ * D_ * 2;   // 25.2 MB bf16
    float* sim    = (float*)p;     p += (size_t)B_ * L_ * L_ * 4;   // 37.7 MB
    float* V      = (float*)p;     p += (size_t)B_ * L_ * L_ * 4;   // 37.7 MB (Vsto)
    float* align_ = (float*)p;     p += (size_t)B_ * L_ * L_ * 4;   // 37.7 MB
    float* wt     = (float*)p;     p += (size_t)A_ * K_ * D_ * 4;   //  1.0 MB
    float* cons   = (float*)p;                                      // 40 KB

    transpose_w_kernel<<<(A_ * K_ * D_ + 255) / 256, 256, 0, stream>>>(conv_w, wt);
    conv_kernel<<<dim3(L_ / 32, B_), 512, 0, stream>>>(matrices, wt, conv_b, ehi, elo);
    sim_kernel<<<dim3(L_ / 64, L_ / 64, B_), 256, 0, stream>>>(ehi, elo, sim);
    nw_fwd_kernel<<<B_, 64, 0, stream>>>(sim, V);
    nw_bwd_kernel<<<B_, 64, 0, stream>>>(sim, V, shapes, align_);
    hipMemsetAsync(cons, 0, (size_t)L_ * A_ * sizeof(float), stream);
    consensus_kernel<<<dim3(L_ / 64, B_), 256, 0, stream>>>(matrices, align_, cons);
    out_kernel<<<dim3(L_ / 32, B_), 256, 0, stream>>>(align_, cons, out);
}

// Round 10
// 1045.863 us; speedup vs baseline: 1.0715x; 1.0715x over previous
//
#include <hip/hip_runtime.h>
#include <hip/hip_bf16.h>
#include <math.h>

#define B_  64
#define A_  26
#define L_  384
#define D_  512
#define K_  18
#define LP1 385   // L_ + 1
#define VS  384   // Vsto row stride; Vsto[i-1][j-1] = V[i][j]

typedef __attribute__((ext_vector_type(8))) short bf16x8;   // 8 bf16 = 4 VGPRs
typedef __attribute__((ext_vector_type(4))) float f32x4;
typedef unsigned short ushort_t;
typedef unsigned int uint_t;

// RNE f32 -> bf16 bits
__device__ __forceinline__ ushort_t f2bf(float v) {
    uint_t u = __float_as_uint(v);
    uint_t r = (u + 0x7FFFu + ((u >> 16) & 1u)) >> 16;
    return (ushort_t)r;
}

// DPP lane shifts (gfx9-family wave shifts, VALU-speed; bound_ctrl -> 0 fill)
__device__ __forceinline__ float dpp_up1(float x) {   // lane i <- lane i-1; lane0 <- 0
    return __int_as_float(__builtin_amdgcn_update_dpp(
        0, __float_as_int(x), 0x138, 0xF, 0xF, true));  // WAVE_SHR1
}
__device__ __forceinline__ float dpp_down1(float x) { // lane i <- lane i+1; lane63 <- 0
    return __int_as_float(__builtin_amdgcn_update_dpp(
        0, __float_as_int(x), 0x130, 0xF, 0xF, true));  // WAVE_SHL1
}

// ---------------- conv weight transpose: (D,A,K) -> (A*K, D) ----------------
__global__ void transpose_w_kernel(const float* __restrict__ w, float* __restrict__ wt) {
    int o = blockIdx.x * blockDim.x + threadIdx.x;   // o = r*D + d
    int total = A_ * K_ * D_;
    if (o >= total) return;
    int d = o % D_;
    int r = o / D_;                                   // r = a*K + k
    wt[o] = w[(size_t)d * (A_ * K_) + r];
}

// ---------------- conv1d -> e_hi/e_lo (B, L, D) bf16 split ----------------
__global__ __launch_bounds__(512) void conv_kernel(const float* __restrict__ x,     // (B, A, L)
                                                   const float* __restrict__ wt,    // (A*K, D)
                                                   const float* __restrict__ bias,  // (D,)
                                                   ushort_t* __restrict__ ehi,      // (B, L, D) bf16
                                                   ushort_t* __restrict__ elo) {    // (B, L, D) bf16
    const int TL = 32;
    const int XW = TL + K_ - 1;     // 49
    int l0 = blockIdx.x * TL;
    int b  = blockIdx.y;
    int d  = threadIdx.x;           // 512 threads, one per output channel
    __shared__ float xs[A_][XW];
    for (int idx = threadIdx.x; idx < A_ * XW; idx += 512) {
        int a = idx / XW, p = idx % XW;
        int g = l0 - (K_ - 1) / 2 + p;  // l0 - 8 + p
        xs[a][p] = (g >= 0 && g < L_) ? x[((size_t)b * A_ + a) * L_ + g] : 0.0f;
    }
    __syncthreads();
    float acc[TL];
#pragma unroll
    for (int l = 0; l < TL; ++l) acc[l] = 0.0f;
#pragma unroll 1
    for (int a = 0; a < A_; ++a) {
        float xr[XW];
#pragma unroll
        for (int p = 0; p < XW; ++p) xr[p] = xs[a][p];
        const float* wrow = wt + (size_t)(a * K_) * D_ + d;
#pragma unroll
        for (int k = 0; k < K_; ++k) {
            float w = wrow[(size_t)k * D_];
#pragma unroll
            for (int l = 0; l < TL; ++l)
                acc[l] = fmaf(xr[k + l], w, acc[l]);
        }
    }
    float bv = bias[d];
#pragma unroll
    for (int l = 0; l < TL; ++l) {
        float v = acc[l] + bv;
        ushort_t h = f2bf(v);
        float hf = __uint_as_float(((uint_t)h) << 16);
        ushort_t lo = f2bf(v - hf);
        size_t idx = ((size_t)b * L_ + (l0 + l)) * D_ + d;
        ehi[idx] = h;
        elo[idx] = lo;
    }
}

// ---------------- sim = E_b · E_0^T via split-bf16 MFMA ----------------
__global__ __launch_bounds__(256) void sim_kernel(const ushort_t* __restrict__ ehi,
                                                  const ushort_t* __restrict__ elo,
                                                  float* __restrict__ sim) {
    int b = blockIdx.z;
    int w = threadIdx.x >> 6;
    int lane = threadIdx.x & 63;
    int l0 = blockIdx.y * 64 + 32 * (w >> 1);
    int m0 = blockIdx.x * 64 + 32 * (w & 1);
    int r = lane & 15, g = lane >> 4;
    size_t rowA = ((size_t)b * L_ + l0 + r) * D_ + g * 8;
    size_t rowB = ((size_t)m0 + r) * D_ + g * 8;      // batch 0
    const ushort_t* pah = ehi + rowA;
    const ushort_t* pal = elo + rowA;
    const ushort_t* pbh = ehi + rowB;
    const ushort_t* pbl = elo + rowB;
    f32x4 acc00 = {0.f, 0.f, 0.f, 0.f}, acc01 = acc00, acc10 = acc00, acc11 = acc00;
#pragma unroll 2
    for (int ks = 0; ks < 16; ++ks) {
        int off = ks * 32;
        bf16x8 Ah0 = *(const bf16x8*)(pah + off);
        bf16x8 Ah1 = *(const bf16x8*)(pah + 16 * D_ + off);
        bf16x8 Al0 = *(const bf16x8*)(pal + off);
        bf16x8 Al1 = *(const bf16x8*)(pal + 16 * D_ + off);
        bf16x8 Bh0 = *(const bf16x8*)(pbh + off);
        bf16x8 Bh1 = *(const bf16x8*)(pbh + 16 * D_ + off);
        bf16x8 Bl0 = *(const bf16x8*)(pbl + off);
        bf16x8 Bl1 = *(const bf16x8*)(pbl + 16 * D_ + off);
        acc00 = __builtin_amdgcn_mfma_f32_16x16x32_bf16(Ah0, Bh0, acc00, 0, 0, 0);
        acc00 = __builtin_amdgcn_mfma_f32_16x16x32_bf16(Ah0, Bl0, acc00, 0, 0, 0);
        acc00 = __builtin_amdgcn_mfma_f32_16x16x32_bf16(Al0, Bh0, acc00, 0, 0, 0);
        acc01 = __builtin_amdgcn_mfma_f32_16x16x32_bf16(Ah0, Bh1, acc01, 0, 0, 0);
        acc01 = __builtin_amdgcn_mfma_f32_16x16x32_bf16(Ah0, Bl1, acc01, 0, 0, 0);
        acc01 = __builtin_amdgcn_mfma_f32_16x16x32_bf16(Al0, Bh1, acc01, 0, 0, 0);
        acc10 = __builtin_amdgcn_mfma_f32_16x16x32_bf16(Ah1, Bh0, acc10, 0, 0, 0);
        acc10 = __builtin_amdgcn_mfma_f32_16x16x32_bf16(Ah1, Bl0, acc10, 0, 0, 0);
        acc10 = __builtin_amdgcn_mfma_f32_16x16x32_bf16(Al1, Bh0, acc10, 0, 0, 0);
        acc11 = __builtin_amdgcn_mfma_f32_16x16x32_bf16(Ah1, Bh1, acc11, 0, 0, 0);
        acc11 = __builtin_amdgcn_mfma_f32_16x16x32_bf16(Ah1, Bl1, acc11, 0, 0, 0);
        acc11 = __builtin_amdgcn_mfma_f32_16x16x32_bf16(Al1, Bh1, acc11, 0, 0, 0);
    }
    float* sp = sim + ((size_t)b * L_ + l0) * L_ + m0;
#pragma unroll
    for (int v = 0; v < 4; ++v) {
        int row = g * 4 + v;
        sp[(size_t)row * L_ + r]             = acc00[v];
        sp[(size_t)row * L_ + 16 + r]        = acc01[v];
        sp[(size_t)(16 + row) * L_ + r]      = acc10[v];
        sp[(size_t)(16 + row) * L_ + 16 + r] = acc11[v];
    }
}

// ---------------- NW forward: one wave/batch, 6 rows/lane, 4-col tiles, 3x-unrolled pipeline ----------------
// V[i,j] = sim[i-1,j-1] + smoothmax3(V[i-1,j-1], V[i-1,j], V[i,j-1])   (g=0, t=1)
// Software pipeline with STATIC buffer sets (unroll x3, 159 = 3*53): each body
// consumes its set (waits on a load issued 3 tiles earlier), immediately re-issues
// that set's loads for T+3, then computes. No register-copy ring -> no early waits.
__global__ __launch_bounds__(64, 1) void nw_fwd_kernel(const float* __restrict__ sim, float* __restrict__ V) {
    int b = blockIdx.x;
    int l = threadIdx.x;
    const float* sb = sim + (size_t)b * L_ * L_;
    float* Vb = V + (size_t)b * L_ * L_;             // Vsto layout
    const float* srow[6];
    float* vrow[6];
#pragma unroll
    for (int r = 0; r < 6; ++r) {
        srow[r] = sb + (size_t)(6 * l + r) * L_;
        vrow[r] = Vb + (size_t)(6 * l + r) * VS;
    }
    float vleft[6] = {0.f, 0.f, 0.f, 0.f, 0.f, 0.f};  // V[i, 0] = 0
    float bcarry[4] = {0.f, 0.f, 0.f, 0.f};           // row-5 V at this tile's cols
    float bprev = 0.f;                                // row-5 V at col c0-1

    auto body = [&](float4* buf, int T) {
        float sc[6][4];
#pragma unroll
        for (int r = 0; r < 6; ++r) {
            float4 t = buf[r];
            sc[r][0] = t.x; sc[r][1] = t.y; sc[r][2] = t.z; sc[r][3] = t.w;
        }
        int cP = min(max(4 * (T + 3 - l), 0), 380);   // re-issue this set for T+3
#pragma unroll
        for (int r = 0; r < 6; ++r) buf[r] = *(const float4*)(srow[r] + cP);
        // cross-lane inputs (whole-wave, outside divergent region)
        float d0 = dpp_up1(bprev);                    // V[6l, c0]
        float uin[4];
#pragma unroll
        for (int q = 0; q < 4; ++q) uin[q] = dpp_up1(bcarry[q]);   // V[6l, c0+q+1]
        int c0 = 4 * (T - l);
        if (c0 >= 0 && c0 <= 380) {
            float vout[6][4];
#pragma unroll
            for (int q = 0; q < 4; ++q) {
                float dg = (q == 0) ? d0 : uin[q - 1];
                float up = uin[q];
#pragma unroll
                for (int r = 0; r < 6; ++r) {
                    float lf = vleft[r];
                    float mx = fmaxf(dg, fmaxf(up, lf));
                    float v = sc[r][q] + mx + __logf(__expf(dg - mx) + __expf(up - mx) + __expf(lf - mx));
                    dg = lf;                          // diag for row r+1
                    up = v;                           // up for row r+1
                    vleft[r] = v;
                    vout[r][q] = v;
                }
            }
            bprev = bcarry[3];
#pragma unroll
            for (int q = 0; q < 4; ++q) bcarry[q] = vout[5][q];
#pragma unroll
            for (int r = 0; r < 6; ++r) {
                float4 t;
                t.x = vout[r][0]; t.y = vout[r][1]; t.z = vout[r][2]; t.w = vout[r][3];
                *(float4*)(vrow[r] + c0) = t;
            }
        }
    };

    float4 buf0[6], buf1[6], buf2[6];
    {
        int cA = min(max(4 * (0 - l), 0), 380);
        int cB = min(max(4 * (1 - l), 0), 380);
        int cC = min(max(4 * (2 - l), 0), 380);
#pragma unroll
        for (int r = 0; r < 6; ++r) {
            buf0[r] = *(const float4*)(srow[r] + cA);
            buf1[r] = *(const float4*)(srow[r] + cB);
            buf2[r] = *(const float4*)(srow[r] + cC);
        }
    }
#pragma unroll 1
    for (int Tb = 0; Tb < 159; Tb += 3) {
        body(buf0, Tb);
        body(buf1, Tb + 1);
        body(buf2, Tb + 2);
    }
}

// ---------------- NW backward: 3 passes x 2 rows/lane, 3x-unrolled pipeline, LDS U/E boundary ----------------
// E[i,j] = [i==li && j==lj] + E[i+1,j+1]*exp(V[i,j]-U[i+1,j+1]) + E[i+1,j]*exp(V[i,j]-U[i+1,j])
//        + E[i,j+1]*exp(V[i,j]-U[i,j+1]),   U[i,j] = V[i,j] - sim0[i-1][j-1].
__global__ __launch_bounds__(64, 1) void nw_bwd_kernel(const float* __restrict__ sim,
                                                       const float* __restrict__ V,
                                                       const int* __restrict__ shapes,
                                                       float* __restrict__ align_) {
    int b = blockIdx.x;
    int l = threadIdx.x;
    const float* sb = sim + (size_t)b * L_ * L_;
    const float* Vb = V + (size_t)b * L_ * L_;       // Vsto layout
    float* ab = align_ + (size_t)b * L_ * L_;
    int li = min(max(shapes[2 * b + 0], 0), L_);
    int lj = min(max(shapes[2 * b + 1], 0), L_);
    __shared__ float Eb[2][388];                     // [parity][j-1] = E[r0+129, j]
    __shared__ float Ub[2][388];                     // [parity][j-1] = U[r0+129, j]
    for (int k = l; k < 2 * 388; k += 64) { ((float*)Eb)[k] = 0.f; ((float*)Ub)[k] = 0.f; }
    bool L63 = (l == 63);
#pragma unroll 1
    for (int pass = 0; pass < 3; ++pass) {
        int r0 = 256 - 128 * pass;
        int i1 = r0 + 2 * l + 1, i2 = i1 + 1;
        const float* pV0 = Vb + (size_t)(r0 + 2 * l) * VS;       // V[i1, *]
        const float* pV1 = Vb + (size_t)(r0 + 2 * l + 1) * VS;   // V[i2, *]
        const float* pS0 = sb + (size_t)(r0 + 2 * l) * L_;       // sim0[i1-1][*]
        const float* pS1 = sb + (size_t)(r0 + 2 * l + 1) * L_;   // sim0[i2-1][*]
        float* pE0 = ab + (size_t)(i1 - 1) * L_;
        float* pE1 = ab + (size_t)(i2 - 1) * L_;
        const float* Ebr = Eb[pass & 1];
        float* Ebw = Eb[(pass & 1) ^ 1];
        const float* Ubr = Ub[pass & 1];
        float* Ubw = Ub[(pass & 1) ^ 1];
        float e0 = 0.f, e1 = 0.f, u0p = 0.f, u1p = 0.f;          // E/U[i*, j+1] carries
        float ecarry[4] = {0.f, 0.f, 0.f, 0.f};                  // E[i1, tile cols] (for lane l-1)
        float ucarry[4] = {0.f, 0.f, 0.f, 0.f};                  // U[i1, tile cols]
        float eprev_s = 0.f, uprev_s = 0.f;                      // E/U[i1, jhi+1] snapshots
        float eb_carry = 0.f, ub_carry = 0.f;                    // lane63 boundary carries

        auto body = [&](float4& fV0, float4& fV1, float4& fS0, float4& fS1, int T) {
            float V0q[4], V1q[4], S0q[4], S1q[4];
            { float4 t = fV0; V0q[0]=t.x; V0q[1]=t.y; V0q[2]=t.z; V0q[3]=t.w; }
            { float4 t = fV1; V1q[0]=t.x; V1q[1]=t.y; V1q[2]=t.z; V1q[3]=t.w; }
            { float4 t = fS0; S0q[0]=t.x; S0q[1]=t.y; S0q[2]=t.z; S0q[3]=t.w; }
            { float4 t = fS1; S1q[0]=t.x; S1q[1]=t.y; S1q[2]=t.z; S1q[3]=t.w; }
            int cP = min(max(380 - 4 * (T + 3 - (63 - l)), 0), 380);  // re-issue for T+3
            fV0 = *(const float4*)(pV0 + cP);
            fV1 = *(const float4*)(pV1 + cP);
            fS0 = *(const float4*)(pS0 + cP);
            fS1 = *(const float4*)(pS1 + cP);
            int c0 = 380 - 4 * (T - (63 - l));
            // cross-lane (whole-wave): lane l+1 covered these cols at T-1
            float enbtd3 = dpp_down1(eprev_s);       // E[i2+1, jhi+1]
            float unbtd3 = dpp_down1(uprev_s);       // U[i2+1, jhi+1]
            float enbc[4], unbc[4];
#pragma unroll
            for (int q = 0; q < 4; ++q) {
                enbc[q] = dpp_down1(ecarry[q]);      // E[i2+1, c0+1+q]
                unbc[q] = dpp_down1(ucarry[q]);      // U[i2+1, c0+1+q]
            }
            eprev_s = e0; uprev_s = u0p;             // snapshot AFTER dpps
            if (c0 >= 0 && c0 <= 380) {
                float ebq[4] = {0.f, 0.f, 0.f, 0.f};
                float ubq[4] = {0.f, 0.f, 0.f, 0.f};
                if (L63) {
                    float4 t = *(const float4*)&Ebr[c0];
                    ebq[0] = t.x; ebq[1] = t.y; ebq[2] = t.z; ebq[3] = t.w;
                    float4 u = *(const float4*)&Ubr[c0];
                    ubq[0] = u.x; ubq[1] = u.y; ubq[2] = u.z; ubq[3] = u.w;
                }
                float u0c[4], u1c[4];
#pragma unroll
                for (int q = 0; q < 4; ++q) {
                    u0c[q] = V0q[q] - S0q[q];        // U[i1, c0+1+q]
                    u1c[q] = V1q[q] - S1q[q];        // U[i2, c0+1+q]
                }
                float Eo0[4], Eo1[4];
#pragma unroll
                for (int qq = 0; qq < 4; ++qq) {
                    const int q = 3 - qq;            // descending cols
                    int j = c0 + 1 + q;
                    float enb   = L63 ? ebq[q] : enbc[q];
                    float unb   = L63 ? ubq[q] : unbc[q];
                    float enbtd = (q == 3) ? (L63 ? eb_carry : enbtd3)
                                           : (L63 ? ebq[q + 1] : enbc[q + 1]);
                    float unbtd = (q == 3) ? (L63 ? ub_carry : unbtd3)
                                           : (L63 ? ubq[q + 1] : unbc[q + 1]);
                    bool jlt = (j < L_), i2lt = (i2 < L_);
                    float wtd1 = (i2lt && jlt) ? __expf(V1q[q] - unbtd) : 0.f;
                    float wtu1 = i2lt ? __expf(V1q[q] - unb) : 0.f;
                    float wtl1 = jlt ? __expf(V1q[q] - u1p) : 0.f;
                    float wtd0 = jlt ? __expf(V0q[q] - u1p) : 0.f;
                    float wtu0 = __expf(V0q[q] - u1c[q]);
                    float wtl0 = jlt ? __expf(V0q[q] - u0p) : 0.f;
                    float ea1 = (i2 == li && j == lj) ? 1.f : 0.f;
                    ea1 += wtd1 * enbtd + wtu1 * enb + wtl1 * e1;
                    float ea0 = (i1 == li && j == lj) ? 1.f : 0.f;
                    ea0 += wtd0 * e1 + wtu0 * ea1 + wtl0 * e0;
                    e1 = ea1; e0 = ea0;
                    u1p = u1c[q]; u0p = u0c[q];
                    Eo1[q] = ea1; Eo0[q] = ea0;
                }
                eb_carry = ebq[0]; ub_carry = ubq[0];
#pragma unroll
                for (int q = 0; q < 4; ++q) { ecarry[q] = Eo0[q]; ucarry[q] = u0c[q]; }
                float4 t0, t1;
                t0.x = Eo0[0]; t0.y = Eo0[1]; t0.z = Eo0[2]; t0.w = Eo0[3];
                t1.x = Eo1[0]; t1.y = Eo1[1]; t1.z = Eo1[2]; t1.w = Eo1[3];
                *(float4*)(pE0 + c0) = t0;
                *(float4*)(pE1 + c0) = t1;
                if (l == 0) {                         // boundary E and U for next pass
                    *(float4*)&Ebw[c0] = t0;
                    float4 tu;
                    tu.x = u0c[0]; tu.y = u0c[1]; tu.z = u0c[2]; tu.w = u0c[3];
                    *(float4*)&Ubw[c0] = tu;
                }
            }
        };

        float4 aV0, aV1, aS0, aS1, bV0x, bV1x, bS0x, bS1x, cV0, cV1, cS0, cS1;
        {
            int c0p = min(max(380 - 4 * (0 - (63 - l)), 0), 380);
            int c1p = min(max(380 - 4 * (1 - (63 - l)), 0), 380);
            int c2p = min(max(380 - 4 * (2 - (63 - l)), 0), 380);
            aV0 = *(const float4*)(pV0 + c0p); aV1 = *(const float4*)(pV1 + c0p);
            aS0 = *(const float4*)(pS0 + c0p); aS1 = *(const float4*)(pS1 + c0p);
            bV0x = *(const float4*)(pV0 + c1p); bV1x = *(const float4*)(pV1 + c1p);
            bS0x = *(const float4*)(pS0 + c1p); bS1x = *(const float4*)(pS1 + c1p);
            cV0 = *(const float4*)(pV0 + c2p); cV1 = *(const float4*)(pV1 + c2p);
            cS0 = *(const float4*)(pS0 + c2p); cS1 = *(const float4*)(pS1 + c2p);
        }
#pragma unroll 1
        for (int Tb = 0; Tb < 159; Tb += 3) {
            body(aV0, aV1, aS0, aS1, Tb);
            body(bV0x, bV1x, bS0x, bS1x, Tb + 1);
            body(cV0, cV1, cS0, cS1, Tb + 2);
        }
    }
}

// ---------------- consensus[j,a] = (1/B) sum_n sum_i matrices[n,a,i]*align[n,i,j] ----------------
__global__ __launch_bounds__(256) void consensus_kernel(const float* __restrict__ x,      // (B,A,L)
                                                        const float* __restrict__ align_, // (B,L,L)
                                                        float* __restrict__ cons) {       // (L,A)
    int n  = blockIdx.y;
    int j0 = blockIdx.x * 64;
    __shared__ float ms[A_][L_];    // 39.9 KB: matrices[n] staged
    for (int idx = threadIdx.x; idx < A_ * L_; idx += 256)
        ((float*)ms)[idx] = x[(size_t)n * A_ * L_ + idx];
    __syncthreads();
    int jl = threadIdx.x & 63;
    int g  = threadIdx.x >> 6;      // 0..3
    int a0 = g * 7;                 // 0,7,14,21
    int na = (a0 + 7 <= A_) ? 7 : (A_ - a0);   // 7,7,7,5
    int j  = j0 + jl;
    float acc[7] = {0.f, 0.f, 0.f, 0.f, 0.f, 0.f, 0.f};
    const float* acol = align_ + (size_t)n * L_ * L_ + j;
    for (int i = 0; i < L_; ++i) {
        float al = acol[(size_t)i * L_];
#pragma unroll
        for (int t = 0; t < 7; ++t)
            if (t < na) acc[t] = fmaf(al, ms[a0 + t][i], acc[t]);
    }
    for (int t = 0; t < na; ++t)
        atomicAdd(&cons[(size_t)j * A_ + a0 + t], acc[t] * (1.0f / B_));
}

// ---------------- out[n,i,a] = sum_j cons[j,a] * align[n,i,j] ----------------
__global__ __launch_bounds__(256) void out_kernel(const float* __restrict__ align_,
                                                  const float* __restrict__ cons,
                                                  float* __restrict__ out) {
    int n  = blockIdx.y;
    int i0 = blockIdx.x * 32;
    __shared__ float cs[L_][A_];        // 40.0 KB
    __shared__ float as_[32][L_ + 1];   // 49.3 KB (pad: break 384-stride bank alias)
    for (int idx = threadIdx.x; idx < L_ * A_; idx += 256)
        ((float*)cs)[idx] = cons[idx];
    for (int idx = threadIdx.x; idx < 32 * L_; idx += 256) {
        int r = idx / L_, c = idx % L_;
        as_[r][c] = align_[((size_t)n * L_ + i0 + r) * L_ + c];
    }
    __syncthreads();
    for (int o = threadIdx.x; o < 32 * A_; o += 256) {
        int il = o / A_, a = o % A_;
        float s = 0.f;
        for (int jj = 0; jj < L_; ++jj)
            s = fmaf(as_[il][jj], cs[jj][a], s);
        out[((size_t)n * L_ + i0 + il) * A_ + a] = s;
    }
}

extern "C" void kernel_launch(void* const* d_in, const int* in_sizes, int n_in,
                              void* d_out, int out_size, void* d_ws, size_t ws_size,
                              hipStream_t stream) {
    const float* matrices = (const float*)d_in[0];   // (B,A,L) f32
    const int*   shapes   = (const int*)d_in[1];     // (B,2) i32
    const float* conv_w   = (const float*)d_in[2];   // (D,A,K) f32
    const float* conv_b   = (const float*)d_in[3];   // (D,) f32
    float* out = (float*)d_out;                      // (B,L,A) f32

    char* p = (char*)d_ws;
    ushort_t* ehi = (ushort_t*)p;  p += (size_t)B_ * L_ * D_ * 2;   // 25.2 MB bf16
    ushort_t* elo = (ushort_t*)p;  p += (size_t)B_ * L_ * D_ * 2;   // 25.2 MB bf16
    float* sim    = (float*)p;     p += (size_t)B_ * L_ * L_ * 4;   // 37.7 MB
    float* V      = (float*)p;     p += (size_t)B_ * L_ * L_ * 4;   // 37.7 MB (Vsto)
    float* align_ = (float*)p;     p += (size_t)B_ * L_ * L_ * 4;   // 37.7 MB
    float* wt     = (float*)p;     p += (size_t)A_ * K_ * D_ * 4;   //  1.0 MB
    float* cons   = (float*)p;                                      // 40 KB

    transpose_w_kernel<<<(A_ * K_ * D_ + 255) / 256, 256, 0, stream>>>(conv_w, wt);
    conv_kernel<<<dim3(L_ / 32, B_), 512, 0, stream>>>(matrices, wt, conv_b, ehi, elo);
    sim_kernel<<<dim3(L_ / 64, L_ / 64, B_), 256, 0, stream>>>(ehi, elo, sim);
    nw_fwd_kernel<<<B_, 64, 0, stream>>>(sim, V);
    nw_bwd_kernel<<<B_, 64, 0, stream>>>(sim, V, shapes, align_);
    hipMemsetAsync(cons, 0, (size_t)L_ * A_ * sizeof(float), stream);
    consensus_kernel<<<dim3(L_ / 64, B_), 256, 0, stream>>>(matrices, align_, cons);
    out_kernel<<<dim3(L_ / 32, B_), 256, 0, stream>>>(align_, cons, out);
}

// Round 11
// 1011.328 us; speedup vs baseline: 1.1081x; 1.0341x over previous
//
#include <hip/hip_runtime.h>
#include <hip/hip_bf16.h>
#include <math.h>

#define B_  64
#define A_  26
#define L_  384
#define D_  512
#define K_  18
#define LL  147456   // L_*L_ per-batch stride

typedef __attribute__((ext_vector_type(8))) short bf16x8;   // 8 bf16 = 4 VGPRs
typedef __attribute__((ext_vector_type(4))) float f32x4;
typedef unsigned short ushort_t;
typedef unsigned int uint_t;

// ---- F layout (fwd-natural): float4 of row z, cols 4ct..4ct+3 at
//      off_F(z,ct) = ((ct*6 + z%6)*64 + z/6)*4   [floats; +q for col 4ct+q]
__device__ __forceinline__ int off_F(int z, int ct) {
    return ((ct * 6 + z % 6) * 64 + z / 6) * 4;
}
// ---- B layout (bwd-natural): off_B(z,ct) = ct*1536 + (z>>7)*512 + (z&1)*256 + ((z&127)>>1)*4
__device__ __forceinline__ int off_B(int z, int ct) {
    return ct * 1536 + ((z >> 7) << 9) + ((z & 1) << 8) + (((z & 127) >> 1) << 2);
}

// RNE f32 -> bf16 bits
__device__ __forceinline__ ushort_t f2bf(float v) {
    uint_t u = __float_as_uint(v);
    uint_t r = (u + 0x7FFFu + ((u >> 16) & 1u)) >> 16;
    return (ushort_t)r;
}

// DPP lane shifts (gfx9-family wave shifts, VALU-speed; bound_ctrl -> 0 fill)
__device__ __forceinline__ float dpp_up1(float x) {   // lane i <- lane i-1; lane0 <- 0
    return __int_as_float(__builtin_amdgcn_update_dpp(
        0, __float_as_int(x), 0x138, 0xF, 0xF, true));  // WAVE_SHR1
}
__device__ __forceinline__ float dpp_down1(float x) { // lane i <- lane i+1; lane63 <- 0
    return __int_as_float(__builtin_amdgcn_update_dpp(
        0, __float_as_int(x), 0x130, 0xF, 0xF, true));  // WAVE_SHL1
}

// ---------------- conv weight transpose: (D,A,K) -> (A*K, D) ----------------
__global__ void transpose_w_kernel(const float* __restrict__ w, float* __restrict__ wt) {
    int o = blockIdx.x * blockDim.x + threadIdx.x;   // o = r*D + d
    int total = A_ * K_ * D_;
    if (o >= total) return;
    int d = o % D_;
    int r = o / D_;                                   // r = a*K + k
    wt[o] = w[(size_t)d * (A_ * K_) + r];
}

// ---------------- conv1d -> e_hi/e_lo (B, L, D) bf16 split ----------------
__global__ __launch_bounds__(512) void conv_kernel(const float* __restrict__ x,     // (B, A, L)
                                                   const float* __restrict__ wt,    // (A*K, D)
                                                   const float* __restrict__ bias,  // (D,)
                                                   ushort_t* __restrict__ ehi,      // (B, L, D) bf16
                                                   ushort_t* __restrict__ elo) {    // (B, L, D) bf16
    const int TL = 32;
    const int XW = TL + K_ - 1;     // 49
    int l0 = blockIdx.x * TL;
    int b  = blockIdx.y;
    int d  = threadIdx.x;           // 512 threads, one per output channel
    __shared__ float xs[A_][XW];
    for (int idx = threadIdx.x; idx < A_ * XW; idx += 512) {
        int a = idx / XW, p = idx % XW;
        int g = l0 - (K_ - 1) / 2 + p;  // l0 - 8 + p
        xs[a][p] = (g >= 0 && g < L_) ? x[((size_t)b * A_ + a) * L_ + g] : 0.0f;
    }
    __syncthreads();
    float acc[TL];
#pragma unroll
    for (int l = 0; l < TL; ++l) acc[l] = 0.0f;
#pragma unroll 1
    for (int a = 0; a < A_; ++a) {
        float xr[XW];
#pragma unroll
        for (int p = 0; p < XW; ++p) xr[p] = xs[a][p];
        const float* wrow = wt + (size_t)(a * K_) * D_ + d;
#pragma unroll
        for (int k = 0; k < K_; ++k) {
            float w = wrow[(size_t)k * D_];
#pragma unroll
            for (int l = 0; l < TL; ++l)
                acc[l] = fmaf(xr[k + l], w, acc[l]);
        }
    }
    float bv = bias[d];
#pragma unroll
    for (int l = 0; l < TL; ++l) {
        float v = acc[l] + bv;
        ushort_t h = f2bf(v);
        float hf = __uint_as_float(((uint_t)h) << 16);
        ushort_t lo = f2bf(v - hf);
        size_t idx = ((size_t)b * L_ + (l0 + l)) * D_ + d;
        ehi[idx] = h;
        elo[idx] = lo;
    }
}

// ---------------- sim = E_b · E_0^T via split-bf16 MFMA; writes simF layout ----------------
__global__ __launch_bounds__(256) void sim_kernel(const ushort_t* __restrict__ ehi,
                                                  const ushort_t* __restrict__ elo,
                                                  float* __restrict__ simF) {
    int b = blockIdx.z;
    int w = threadIdx.x >> 6;
    int lane = threadIdx.x & 63;
    int l0 = blockIdx.y * 64 + 32 * (w >> 1);
    int m0 = blockIdx.x * 64 + 32 * (w & 1);
    int r = lane & 15, g = lane >> 4;
    size_t rowA = ((size_t)b * L_ + l0 + r) * D_ + g * 8;
    size_t rowB = ((size_t)m0 + r) * D_ + g * 8;      // batch 0
    const ushort_t* pah = ehi + rowA;
    const ushort_t* pal = elo + rowA;
    const ushort_t* pbh = ehi + rowB;
    const ushort_t* pbl = elo + rowB;
    f32x4 acc00 = {0.f, 0.f, 0.f, 0.f}, acc01 = acc00, acc10 = acc00, acc11 = acc00;
#pragma unroll 2
    for (int ks = 0; ks < 16; ++ks) {
        int off = ks * 32;
        bf16x8 Ah0 = *(const bf16x8*)(pah + off);
        bf16x8 Ah1 = *(const bf16x8*)(pah + 16 * D_ + off);
        bf16x8 Al0 = *(const bf16x8*)(pal + off);
        bf16x8 Al1 = *(const bf16x8*)(pal + 16 * D_ + off);
        bf16x8 Bh0 = *(const bf16x8*)(pbh + off);
        bf16x8 Bh1 = *(const bf16x8*)(pbh + 16 * D_ + off);
        bf16x8 Bl0 = *(const bf16x8*)(pbl + off);
        bf16x8 Bl1 = *(const bf16x8*)(pbl + 16 * D_ + off);
        acc00 = __builtin_amdgcn_mfma_f32_16x16x32_bf16(Ah0, Bh0, acc00, 0, 0, 0);
        acc00 = __builtin_amdgcn_mfma_f32_16x16x32_bf16(Ah0, Bl0, acc00, 0, 0, 0);
        acc00 = __builtin_amdgcn_mfma_f32_16x16x32_bf16(Al0, Bh0, acc00, 0, 0, 0);
        acc01 = __builtin_amdgcn_mfma_f32_16x16x32_bf16(Ah0, Bh1, acc01, 0, 0, 0);
        acc01 = __builtin_amdgcn_mfma_f32_16x16x32_bf16(Ah0, Bl1, acc01, 0, 0, 0);
        acc01 = __builtin_amdgcn_mfma_f32_16x16x32_bf16(Al0, Bh1, acc01, 0, 0, 0);
        acc10 = __builtin_amdgcn_mfma_f32_16x16x32_bf16(Ah1, Bh0, acc10, 0, 0, 0);
        acc10 = __builtin_amdgcn_mfma_f32_16x16x32_bf16(Ah1, Bl0, acc10, 0, 0, 0);
        acc10 = __builtin_amdgcn_mfma_f32_16x16x32_bf16(Al1, Bh0, acc10, 0, 0, 0);
        acc11 = __builtin_amdgcn_mfma_f32_16x16x32_bf16(Ah1, Bh1, acc11, 0, 0, 0);
        acc11 = __builtin_amdgcn_mfma_f32_16x16x32_bf16(Ah1, Bl1, acc11, 0, 0, 0);
        acc11 = __builtin_amdgcn_mfma_f32_16x16x32_bf16(Al1, Bh1, acc11, 0, 0, 0);
    }
    float* sp = simF + (size_t)b * LL;
#pragma unroll
    for (int v = 0; v < 4; ++v) {
        int ar0 = l0 + g * 4 + v, ar1 = ar0 + 16;
        int ac0 = m0 + r,         ac1 = ac0 + 16;
        sp[off_F(ar0, ac0 >> 2) + (ac0 & 3)] = acc00[v];
        sp[off_F(ar0, ac1 >> 2) + (ac1 & 3)] = acc01[v];
        sp[off_F(ar1, ac0 >> 2) + (ac0 & 3)] = acc10[v];
        sp[off_F(ar1, ac1 >> 2) + (ac1 & 3)] = acc11[v];
    }
}

// ---------------- NW forward: 6 rows/lane, 4-col tiles, 3x-unrolled pipeline, F-layout I/O ----------------
// V[i,j] = sim[i-1,j-1] + smoothmax3(V[i-1,j-1], V[i-1,j], V[i,j-1])   (g=0, t=1)
// simF/VF: instruction r accesses (ct*6+r)*256 + 4l -> 64 consecutive float4s (dense, 16 lines).
__global__ __launch_bounds__(64, 1) void nw_fwd_kernel(const float* __restrict__ simF, float* __restrict__ VF) {
    int b = blockIdx.x;
    int l = threadIdx.x;
    const float* pS = simF + (size_t)b * LL + l * 4;   // + (ct*6+r)*256
    float*       pV = VF   + (size_t)b * LL + l * 4;
    float vleft[6] = {0.f, 0.f, 0.f, 0.f, 0.f, 0.f};  // V[i, 0] = 0
    float bcarry[4] = {0.f, 0.f, 0.f, 0.f};           // row-5 V at this tile's cols
    float bprev = 0.f;                                // row-5 V at col c0-1

    auto body = [&](float4* buf, int T) {
        float sc[6][4];
#pragma unroll
        for (int r = 0; r < 6; ++r) {
            float4 t = buf[r];
            sc[r][0] = t.x; sc[r][1] = t.y; sc[r][2] = t.z; sc[r][3] = t.w;
        }
        int ctP = min(max(T + 3 - l, 0), 95);         // re-issue this set for T+3
#pragma unroll
        for (int r = 0; r < 6; ++r) buf[r] = *(const float4*)(pS + (ctP * 6 + r) * 256);
        // cross-lane inputs (whole-wave, outside divergent region)
        float d0 = dpp_up1(bprev);                    // V[6l, c0]
        float uin[4];
#pragma unroll
        for (int q = 0; q < 4; ++q) uin[q] = dpp_up1(bcarry[q]);   // V[6l, c0+q+1]
        int c0 = 4 * (T - l);
        if (c0 >= 0 && c0 <= 380) {
            int ct0 = c0 >> 2;
            float vout[6][4];
#pragma unroll
            for (int q = 0; q < 4; ++q) {
                float dg = (q == 0) ? d0 : uin[q - 1];
                float up = uin[q];
#pragma unroll
                for (int r = 0; r < 6; ++r) {
                    float lf = vleft[r];
                    float mx = fmaxf(dg, fmaxf(up, lf));
                    float v = sc[r][q] + mx + __logf(__expf(dg - mx) + __expf(up - mx) + __expf(lf - mx));
                    dg = lf;                          // diag for row r+1
                    up = v;                           // up for row r+1
                    vleft[r] = v;
                    vout[r][q] = v;
                }
            }
            bprev = bcarry[3];
#pragma unroll
            for (int q = 0; q < 4; ++q) bcarry[q] = vout[5][q];
#pragma unroll
            for (int r = 0; r < 6; ++r) {
                float4 t;
                t.x = vout[r][0]; t.y = vout[r][1]; t.z = vout[r][2]; t.w = vout[r][3];
                *(float4*)(pV + (ct0 * 6 + r) * 256) = t;
            }
        }
    };

    float4 buf0[6], buf1[6], buf2[6];
    {
        int cA = min(max(0 - l, 0), 95);
        int cB = min(max(1 - l, 0), 95);
        int cC = min(max(2 - l, 0), 95);
#pragma unroll
        for (int r = 0; r < 6; ++r) {
            buf0[r] = *(const float4*)(pS + (cA * 6 + r) * 256);
            buf1[r] = *(const float4*)(pS + (cB * 6 + r) * 256);
            buf2[r] = *(const float4*)(pS + (cC * 6 + r) * 256);
        }
    }
#pragma unroll 1
    for (int Tb = 0; Tb < 159; Tb += 3) {
        body(buf0, Tb);
        body(buf1, Tb + 1);
        body(buf2, Tb + 2);
    }
}

// ---------------- NW backward: 3 passes x 2 rows/lane, 3x-unrolled pipeline, F-layout in, B-layout out ----------------
// E[i,j] = [i==li && j==lj] + E[i+1,j+1]*exp(V[i,j]-U[i+1,j+1]) + E[i+1,j]*exp(V[i,j]-U[i+1,j])
//        + E[i,j+1]*exp(V[i,j]-U[i,j+1]),   U[i,j] = V[i,j] - sim0[i-1][j-1].
__global__ __launch_bounds__(64, 1) void nw_bwd_kernel(const float* __restrict__ simF,
                                                       const float* __restrict__ VF,
                                                       const int* __restrict__ shapes,
                                                       float* __restrict__ alignB) {
    int b = blockIdx.x;
    int l = threadIdx.x;
    const float* sB = simF + (size_t)b * LL;
    const float* vB = VF   + (size_t)b * LL;
    float* aB = alignB + (size_t)b * LL;
    int li = min(max(shapes[2 * b + 0], 0), L_);
    int lj = min(max(shapes[2 * b + 1], 0), L_);
    __shared__ float Eb[2][388];                     // [parity][j-1] = E[r0+129, j]
    __shared__ float Ub[2][388];                     // [parity][j-1] = U[r0+129, j]
    for (int k = l; k < 2 * 388; k += 64) { ((float*)Eb)[k] = 0.f; ((float*)Ub)[k] = 0.f; }
    bool L63 = (l == 63);
#pragma unroll 1
    for (int pass = 0; pass < 3; ++pass) {
        int r0 = 256 - 128 * pass;
        int i1 = r0 + 2 * l + 1, i2 = i1 + 1;
        int z0 = r0 + 2 * l;                         // Vsto/sim row for i1 stream
        int bo0 = off_F(z0, 0);                      // + ct*1536 walks col tiles
        int bo1 = off_F(z0 + 1, 0);
        float* pB0 = aB + ((2 - pass) << 9) + l * 4; // E row z0 (parity 0); +256 for z0+1
        const float* Ebr = Eb[pass & 1];
        float* Ebw = Eb[(pass & 1) ^ 1];
        const float* Ubr = Ub[pass & 1];
        float* Ubw = Ub[(pass & 1) ^ 1];
        float e0 = 0.f, e1 = 0.f, u0p = 0.f, u1p = 0.f;          // E/U[i*, j+1] carries
        float ecarry[4] = {0.f, 0.f, 0.f, 0.f};                  // E[i1, tile cols] (for lane l-1)
        float ucarry[4] = {0.f, 0.f, 0.f, 0.f};                  // U[i1, tile cols]
        float eprev_s = 0.f, uprev_s = 0.f;                      // E/U[i1, jhi+1] snapshots
        float eb_carry = 0.f, ub_carry = 0.f;                    // lane63 boundary carries

        auto body = [&](float4& fV0, float4& fV1, float4& fS0, float4& fS1, int T) {
            float V0q[4], V1q[4], S0q[4], S1q[4];
            { float4 t = fV0; V0q[0]=t.x; V0q[1]=t.y; V0q[2]=t.z; V0q[3]=t.w; }
            { float4 t = fV1; V1q[0]=t.x; V1q[1]=t.y; V1q[2]=t.z; V1q[3]=t.w; }
            { float4 t = fS0; S0q[0]=t.x; S0q[1]=t.y; S0q[2]=t.z; S0q[3]=t.w; }
            { float4 t = fS1; S1q[0]=t.x; S1q[1]=t.y; S1q[2]=t.z; S1q[3]=t.w; }
            int ctP = min(max(95 - (T + 3 - (63 - l)), 0), 95);  // re-issue for T+3
            fV0 = *(const float4*)(vB + ctP * 1536 + bo0);
            fV1 = *(const float4*)(vB + ctP * 1536 + bo1);
            fS0 = *(const float4*)(sB + ctP * 1536 + bo0);
            fS1 = *(const float4*)(sB + ctP * 1536 + bo1);
            int c0 = 380 - 4 * (T - (63 - l));
            // cross-lane (whole-wave): lane l+1 covered these cols at T-1
            float enbtd3 = dpp_down1(eprev_s);       // E[i2+1, jhi+1]
            float unbtd3 = dpp_down1(uprev_s);       // U[i2+1, jhi+1]
            float enbc[4], unbc[4];
#pragma unroll
            for (int q = 0; q < 4; ++q) {
                enbc[q] = dpp_down1(ecarry[q]);      // E[i2+1, c0+1+q]
                unbc[q] = dpp_down1(ucarry[q]);      // U[i2+1, c0+1+q]
            }
            eprev_s = e0; uprev_s = u0p;             // snapshot AFTER dpps
            if (c0 >= 0 && c0 <= 380) {
                int ct0 = c0 >> 2;
                float ebq[4] = {0.f, 0.f, 0.f, 0.f};
                float ubq[4] = {0.f, 0.f, 0.f, 0.f};
                if (L63) {
                    float4 t = *(const float4*)&Ebr[c0];
                    ebq[0] = t.x; ebq[1] = t.y; ebq[2] = t.z; ebq[3] = t.w;
                    float4 u = *(const float4*)&Ubr[c0];
                    ubq[0] = u.x; ubq[1] = u.y; ubq[2] = u.z; ubq[3] = u.w;
                }
                float u0c[4], u1c[4];
#pragma unroll
                for (int q = 0; q < 4; ++q) {
                    u0c[q] = V0q[q] - S0q[q];        // U[i1, c0+1+q]
                    u1c[q] = V1q[q] - S1q[q];        // U[i2, c0+1+q]
                }
                float Eo0[4], Eo1[4];
#pragma unroll
                for (int qq = 0; qq < 4; ++qq) {
                    const int q = 3 - qq;            // descending cols
                    int j = c0 + 1 + q;
                    float enb   = L63 ? ebq[q] : enbc[q];
                    float unb   = L63 ? ubq[q] : unbc[q];
                    float enbtd = (q == 3) ? (L63 ? eb_carry : enbtd3)
                                           : (L63 ? ebq[q + 1] : enbc[q + 1]);
                    float unbtd = (q == 3) ? (L63 ? ub_carry : unbtd3)
                                           : (L63 ? ubq[q + 1] : unbc[q + 1]);
                    bool jlt = (j < L_), i2lt = (i2 < L_);
                    float wtd1 = (i2lt && jlt) ? __expf(V1q[q] - unbtd) : 0.f;
                    float wtu1 = i2lt ? __expf(V1q[q] - unb) : 0.f;
                    float wtl1 = jlt ? __expf(V1q[q] - u1p) : 0.f;
                    float wtd0 = jlt ? __expf(V0q[q] - u1p) : 0.f;
                    float wtu0 = __expf(V0q[q] - u1c[q]);
                    float wtl0 = jlt ? __expf(V0q[q] - u0p) : 0.f;
                    float ea1 = (i2 == li && j == lj) ? 1.f : 0.f;
                    ea1 += wtd1 * enbtd + wtu1 * enb + wtl1 * e1;
                    float ea0 = (i1 == li && j == lj) ? 1.f : 0.f;
                    ea0 += wtd0 * e1 + wtu0 * ea1 + wtl0 * e0;
                    e1 = ea1; e0 = ea0;
                    u1p = u1c[q]; u0p = u0c[q];
                    Eo1[q] = ea1; Eo0[q] = ea0;
                }
                eb_carry = ebq[0]; ub_carry = ubq[0];
#pragma unroll
                for (int q = 0; q < 4; ++q) { ecarry[q] = Eo0[q]; ucarry[q] = u0c[q]; }
                float4 t0, t1;
                t0.x = Eo0[0]; t0.y = Eo0[1]; t0.z = Eo0[2]; t0.w = Eo0[3];
                t1.x = Eo1[0]; t1.y = Eo1[1]; t1.z = Eo1[2]; t1.w = Eo1[3];
                *(float4*)(pB0 + ct0 * 1536)       = t0;   // E row z0   (coalesced)
                *(float4*)(pB0 + 256 + ct0 * 1536) = t1;   // E row z0+1 (coalesced)
                if (l == 0) {                         // boundary E and U for next pass
                    *(float4*)&Ebw[c0] = t0;
                    float4 tu;
                    tu.x = u0c[0]; tu.y = u0c[1]; tu.z = u0c[2]; tu.w = u0c[3];
                    *(float4*)&Ubw[c0] = tu;
                }
            }
        };

        float4 aV0, aV1, aS0, aS1, bV0x, bV1x, bS0x, bS1x, cV0, cV1, cS0, cS1;
        {
            int c0p = min(max(95 - (0 - (63 - l)), 0), 95);
            int c1p = min(max(95 - (1 - (63 - l)), 0), 95);
            int c2p = min(max(95 - (2 - (63 - l)), 0), 95);
            aV0 = *(const float4*)(vB + c0p * 1536 + bo0); aV1 = *(const float4*)(vB + c0p * 1536 + bo1);
            aS0 = *(const float4*)(sB + c0p * 1536 + bo0); aS1 = *(const float4*)(sB + c0p * 1536 + bo1);
            bV0x = *(const float4*)(vB + c1p * 1536 + bo0); bV1x = *(const float4*)(vB + c1p * 1536 + bo1);
            bS0x = *(const float4*)(sB + c1p * 1536 + bo0); bS1x = *(const float4*)(sB + c1p * 1536 + bo1);
            cV0 = *(const float4*)(vB + c2p * 1536 + bo0); cV1 = *(const float4*)(vB + c2p * 1536 + bo1);
            cS0 = *(const float4*)(sB + c2p * 1536 + bo0); cS1 = *(const float4*)(sB + c2p * 1536 + bo1);
        }
#pragma unroll 1
        for (int Tb = 0; Tb < 159; Tb += 3) {
            body(aV0, aV1, aS0, aS1, Tb);
            body(bV0x, bV1x, bS0x, bS1x, Tb + 1);
            body(cV0, cV1, cS0, cS1, Tb + 2);
        }
    }
}

// ---------------- consensus[j,a] = (1/B) sum_n sum_i matrices[n,a,i]*align[n,i,j] (EB layout) ----------------
__global__ __launch_bounds__(256) void consensus_kernel(const float* __restrict__ x,      // (B,A,L)
                                                        const float* __restrict__ alignB, // EB layout
                                                        float* __restrict__ cons) {       // (L,A)
    int n  = blockIdx.y;
    int j0 = blockIdx.x * 64;
    __shared__ float ms[A_][L_];    // 39.9 KB: matrices[n] staged
    for (int idx = threadIdx.x; idx < A_ * L_; idx += 256)
        ((float*)ms)[idx] = x[(size_t)n * A_ * L_ + idx];
    __syncthreads();
    int jl = threadIdx.x & 63;
    int g  = threadIdx.x >> 6;      // 0..3
    int a0 = g * 7;                 // 0,7,14,21
    int na = (a0 + 7 <= A_) ? 7 : (A_ - a0);   // 7,7,7,5
    int j  = j0 + jl;
    float acc[7] = {0.f, 0.f, 0.f, 0.f, 0.f, 0.f, 0.f};
    const float* aB = alignB + (size_t)n * LL + ((j >> 2) * 1536 + (j & 3));
    for (int i = 0; i < L_; ++i) {
        float al = aB[((i >> 7) << 9) + ((i & 1) << 8) + (((i & 127) >> 1) << 2)];
#pragma unroll
        for (int t = 0; t < 7; ++t)
            if (t < na) acc[t] = fmaf(al, ms[a0 + t][i], acc[t]);
    }
    for (int t = 0; t < na; ++t)
        atomicAdd(&cons[(size_t)j * A_ + a0 + t], acc[t] * (1.0f / B_));
}

// ---------------- out[n,i,a] = sum_j cons[j,a] * align[n,i,j] (EB layout read) ----------------
__global__ __launch_bounds__(256) void out_kernel(const float* __restrict__ alignB,
                                                  const float* __restrict__ cons,
                                                  float* __restrict__ out) {
    int n  = blockIdx.y;
    int i0 = blockIdx.x * 32;
    __shared__ float cs[L_][A_];        // 40.0 KB
    __shared__ float as_[32][L_ + 1];   // 49.3 KB (pad: break 384-stride bank alias)
    for (int idx = threadIdx.x; idx < L_ * A_; idx += 256)
        ((float*)cs)[idx] = cons[idx];
    const float* aB = alignB + (size_t)n * LL;
    for (int idx = threadIdx.x; idx < 32 * L_; idx += 256) {
        int r = idx / L_, c = idx % L_;
        int z = i0 + r;
        as_[r][c] = aB[(c >> 2) * 1536 + ((z >> 7) << 9) + ((z & 1) << 8) + (((z & 127) >> 1) << 2) + (c & 3)];
    }
    __syncthreads();
    for (int o = threadIdx.x; o < 32 * A_; o += 256) {
        int il = o / A_, a = o % A_;
        float s = 0.f;
        for (int jj = 0; jj < L_; ++jj)
            s = fmaf(as_[il][jj], cs[jj][a], s);
        out[((size_t)n * L_ + i0 + il) * A_ + a] = s;
    }
}

extern "C" void kernel_launch(void* const* d_in, const int* in_sizes, int n_in,
                              void* d_out, int out_size, void* d_ws, size_t ws_size,
                              hipStream_t stream) {
    const float* matrices = (const float*)d_in[0];   // (B,A,L) f32
    const int*   shapes   = (const int*)d_in[1];     // (B,2) i32
    const float* conv_w   = (const float*)d_in[2];   // (D,A,K) f32
    const float* conv_b   = (const float*)d_in[3];   // (D,) f32
    float* out = (float*)d_out;                      // (B,L,A) f32

    char* p = (char*)d_ws;
    ushort_t* ehi = (ushort_t*)p;  p += (size_t)B_ * L_ * D_ * 2;   // 25.2 MB bf16
    ushort_t* elo = (ushort_t*)p;  p += (size_t)B_ * L_ * D_ * 2;   // 25.2 MB bf16
    float* simF   = (float*)p;     p += (size_t)B_ * LL * 4;        // 37.7 MB (F layout)
    float* VF     = (float*)p;     p += (size_t)B_ * LL * 4;        // 37.7 MB (F layout)
    float* alignB = (float*)p;     p += (size_t)B_ * LL * 4;        // 37.7 MB (B layout)
    float* wt     = (float*)p;     p += (size_t)A_ * K_ * D_ * 4;   //  1.0 MB
    float* cons   = (float*)p;                                      // 40 KB

    transpose_w_kernel<<<(A_ * K_ * D_ + 255) / 256, 256, 0, stream>>>(conv_w, wt);
    conv_kernel<<<dim3(L_ / 32, B_), 512, 0, stream>>>(matrices, wt, conv_b, ehi, elo);
    sim_kernel<<<dim3(L_ / 64, L_ / 64, B_), 256, 0, stream>>>(ehi, elo, simF);
    nw_fwd_kernel<<<B_, 64, 0, stream>>>(simF, VF);
    nw_bwd_kernel<<<B_, 64, 0, stream>>>(simF, VF, shapes, alignB);
    hipMemsetAsync(cons, 0, (size_t)L_ * A_ * sizeof(float), stream);
    consensus_kernel<<<dim3(L_ / 64, B_), 256, 0, stream>>>(matrices, alignB, cons);
    out_kernel<<<dim3(L_ / 32, B_), 256, 0, stream>>>(alignB, cons, out);
}

// Round 12
// 990.813 us; speedup vs baseline: 1.1311x; 1.0207x over previous
//
#include <hip/hip_runtime.h>
#include <hip/hip_bf16.h>
#include <math.h>

#define B_  64
#define A_  26
#define L_  384
#define D_  512
#define K_  18
#define SZD 245760   // per-batch diagonal-layout stride: 160 diags x 1536 floats

typedef __attribute__((ext_vector_type(8))) short bf16x8;   // 8 bf16 = 4 VGPRs
typedef __attribute__((ext_vector_type(4))) float f32x4;
typedef unsigned short ushort_t;
typedef unsigned int uint_t;

// Diagonal layout: matrix element (row z, col c), with l=z/6, r=z%6, ct=c/4:
//   addr = (l+ct)*1536 + r*256 + l*4 + (c&3).   d = l+ct is the anti-diagonal
// index of the wavefront: lane-INVARIANT at any pipeline step for both NW sweeps,
// so every per-tile load/store is 64 consecutive float4 (8 cache lines, dense).
__device__ __forceinline__ void stD(float* sp, int z, int c, float v) {
    int dl = z / 6, dr = z - dl * 6;
    sp[(size_t)(dl + (c >> 2)) * 1536 + dr * 256 + dl * 4 + (c & 3)] = v;
}

// RNE f32 -> bf16 bits
__device__ __forceinline__ ushort_t f2bf(float v) {
    uint_t u = __float_as_uint(v);
    uint_t r = (u + 0x7FFFu + ((u >> 16) & 1u)) >> 16;
    return (ushort_t)r;
}

// DPP lane shifts (VALU-speed; bound_ctrl -> 0 fill)
__device__ __forceinline__ float dpp_up1(float x) {   // lane i <- lane i-1; lane0 <- 0
    return __int_as_float(__builtin_amdgcn_update_dpp(
        0, __float_as_int(x), 0x138, 0xF, 0xF, true));  // WAVE_SHR1
}
__device__ __forceinline__ float dpp_down1(float x) { // lane i <- lane i+1; lane63 <- 0
    return __int_as_float(__builtin_amdgcn_update_dpp(
        0, __float_as_int(x), 0x130, 0xF, 0xF, true));  // WAVE_SHL1
}

// ---------------- conv weight transpose: (D,A,K) -> (A*K, D) ----------------
__global__ void transpose_w_kernel(const float* __restrict__ w, float* __restrict__ wt) {
    int o = blockIdx.x * blockDim.x + threadIdx.x;   // o = r*D + d
    int total = A_ * K_ * D_;
    if (o >= total) return;
    int d = o % D_;
    int r = o / D_;                                   // r = a*K + k
    wt[o] = w[(size_t)d * (A_ * K_) + r];
}

// ---------------- conv1d -> e_hi/e_lo (B, L, D) bf16 split ----------------
__global__ __launch_bounds__(512) void conv_kernel(const float* __restrict__ x,     // (B, A, L)
                                                   const float* __restrict__ wt,    // (A*K, D)
                                                   const float* __restrict__ bias,  // (D,)
                                                   ushort_t* __restrict__ ehi,      // (B, L, D) bf16
                                                   ushort_t* __restrict__ elo) {    // (B, L, D) bf16
    const int TL = 32;
    const int XW = TL + K_ - 1;     // 49
    int l0 = blockIdx.x * TL;
    int b  = blockIdx.y;
    int d  = threadIdx.x;           // 512 threads, one per output channel
    __shared__ float xs[A_][XW];
    for (int idx = threadIdx.x; idx < A_ * XW; idx += 512) {
        int a = idx / XW, p = idx % XW;
        int g = l0 - (K_ - 1) / 2 + p;  // l0 - 8 + p
        xs[a][p] = (g >= 0 && g < L_) ? x[((size_t)b * A_ + a) * L_ + g] : 0.0f;
    }
    __syncthreads();
    float acc[TL];
#pragma unroll
    for (int l = 0; l < TL; ++l) acc[l] = 0.0f;
#pragma unroll 1
    for (int a = 0; a < A_; ++a) {
        float xr[XW];
#pragma unroll
        for (int p = 0; p < XW; ++p) xr[p] = xs[a][p];
        const float* wrow = wt + (size_t)(a * K_) * D_ + d;
#pragma unroll
        for (int k = 0; k < K_; ++k) {
            float w = wrow[(size_t)k * D_];
#pragma unroll
            for (int l = 0; l < TL; ++l)
                acc[l] = fmaf(xr[k + l], w, acc[l]);
        }
    }
    float bv = bias[d];
#pragma unroll
    for (int l = 0; l < TL; ++l) {
        float v = acc[l] + bv;
        ushort_t h = f2bf(v);
        float hf = __uint_as_float(((uint_t)h) << 16);
        ushort_t lo = f2bf(v - hf);
        size_t idx = ((size_t)b * L_ + (l0 + l)) * D_ + d;
        ehi[idx] = h;
        elo[idx] = lo;
    }
}

// ---------------- sim = E_b · E_0^T via split-bf16 MFMA; writes diagonal layout ----------------
__global__ __launch_bounds__(256) void sim_kernel(const ushort_t* __restrict__ ehi,
                                                  const ushort_t* __restrict__ elo,
                                                  float* __restrict__ simD) {
    int b = blockIdx.z;
    int w = threadIdx.x >> 6;
    int lane = threadIdx.x & 63;
    int l0 = blockIdx.y * 64 + 32 * (w >> 1);
    int m0 = blockIdx.x * 64 + 32 * (w & 1);
    int r = lane & 15, g = lane >> 4;
    size_t rowA = ((size_t)b * L_ + l0 + r) * D_ + g * 8;
    size_t rowB = ((size_t)m0 + r) * D_ + g * 8;      // batch 0
    const ushort_t* pah = ehi + rowA;
    const ushort_t* pal = elo + rowA;
    const ushort_t* pbh = ehi + rowB;
    const ushort_t* pbl = elo + rowB;
    f32x4 acc00 = {0.f, 0.f, 0.f, 0.f}, acc01 = acc00, acc10 = acc00, acc11 = acc00;
#pragma unroll 2
    for (int ks = 0; ks < 16; ++ks) {
        int off = ks * 32;
        bf16x8 Ah0 = *(const bf16x8*)(pah + off);
        bf16x8 Ah1 = *(const bf16x8*)(pah + 16 * D_ + off);
        bf16x8 Al0 = *(const bf16x8*)(pal + off);
        bf16x8 Al1 = *(const bf16x8*)(pal + 16 * D_ + off);
        bf16x8 Bh0 = *(const bf16x8*)(pbh + off);
        bf16x8 Bh1 = *(const bf16x8*)(pbh + 16 * D_ + off);
        bf16x8 Bl0 = *(const bf16x8*)(pbl + off);
        bf16x8 Bl1 = *(const bf16x8*)(pbl + 16 * D_ + off);
        acc00 = __builtin_amdgcn_mfma_f32_16x16x32_bf16(Ah0, Bh0, acc00, 0, 0, 0);
        acc00 = __builtin_amdgcn_mfma_f32_16x16x32_bf16(Ah0, Bl0, acc00, 0, 0, 0);
        acc00 = __builtin_amdgcn_mfma_f32_16x16x32_bf16(Al0, Bh0, acc00, 0, 0, 0);
        acc01 = __builtin_amdgcn_mfma_f32_16x16x32_bf16(Ah0, Bh1, acc01, 0, 0, 0);
        acc01 = __builtin_amdgcn_mfma_f32_16x16x32_bf16(Ah0, Bl1, acc01, 0, 0, 0);
        acc01 = __builtin_amdgcn_mfma_f32_16x16x32_bf16(Al0, Bh1, acc01, 0, 0, 0);
        acc10 = __builtin_amdgcn_mfma_f32_16x16x32_bf16(Ah1, Bh0, acc10, 0, 0, 0);
        acc10 = __builtin_amdgcn_mfma_f32_16x16x32_bf16(Ah1, Bl0, acc10, 0, 0, 0);
        acc10 = __builtin_amdgcn_mfma_f32_16x16x32_bf16(Al1, Bh0, acc10, 0, 0, 0);
        acc11 = __builtin_amdgcn_mfma_f32_16x16x32_bf16(Ah1, Bh1, acc11, 0, 0, 0);
        acc11 = __builtin_amdgcn_mfma_f32_16x16x32_bf16(Ah1, Bl1, acc11, 0, 0, 0);
        acc11 = __builtin_amdgcn_mfma_f32_16x16x32_bf16(Al1, Bh1, acc11, 0, 0, 0);
    }
    float* sp = simD + (size_t)b * SZD;
#pragma unroll
    for (int v = 0; v < 4; ++v) {
        int ar0 = l0 + g * 4 + v, ar1 = ar0 + 16;
        int ac0 = m0 + r,         ac1 = ac0 + 16;
        stD(sp, ar0, ac0, acc00[v]);
        stD(sp, ar0, ac1, acc01[v]);
        stD(sp, ar1, ac0, acc10[v]);
        stD(sp, ar1, ac1, acc11[v]);
    }
}

// ---------------- NW forward: 6 rows/lane, 4-col tiles, diag layout, 3x-unrolled pipeline ----------------
// V[i,j] = sim[i-1,j-1] + smoothmax3(V[i-1,j-1], V[i-1,j], V[i,j-1])   (g=0, t=1)
// Lane l at body Tb works tile ct=Tb-l -> diag d=Tb is lane-invariant: every load
// (sim) and store (V) is 64 consecutive float4 = 8 dense lines per instruction.
__global__ __launch_bounds__(64, 1) void nw_fwd_kernel(const float* __restrict__ simD, float* __restrict__ VD) {
    int b = blockIdx.x;
    int l = threadIdx.x;
    const float* pS = simD + (size_t)b * SZD + l * 4;   // + d*1536 + r*256
    float*       pV = VD   + (size_t)b * SZD + l * 4;
    float vleft[6] = {0.f, 0.f, 0.f, 0.f, 0.f, 0.f};  // V[i, 0] = 0
    float bcarry[4] = {0.f, 0.f, 0.f, 0.f};           // row-5 V at this tile's cols
    float bprev = 0.f;                                // row-5 V at col c0-1

    auto body = [&](float4* buf, int Tb) {
        float sc[6][4];
#pragma unroll
        for (int r = 0; r < 6; ++r) {
            float4 t = buf[r];
            sc[r][0] = t.x; sc[r][1] = t.y; sc[r][2] = t.z; sc[r][3] = t.w;
        }
        int dP = min(Tb + 3, 158);                    // re-issue this set for Tb+3
#pragma unroll
        for (int r = 0; r < 6; ++r) buf[r] = *(const float4*)(pS + dP * 1536 + r * 256);
        // cross-lane inputs (whole-wave, outside divergent region)
        float d0 = dpp_up1(bprev);                    // V[6l, c0]
        float uin[4];
#pragma unroll
        for (int q = 0; q < 4; ++q) uin[q] = dpp_up1(bcarry[q]);   // V[6l, c0+q+1]
        int c0 = 4 * (Tb - l);
        if (c0 >= 0 && c0 <= 380) {
            float vout[6][4];
#pragma unroll
            for (int q = 0; q < 4; ++q) {
                float dg = (q == 0) ? d0 : uin[q - 1];
                float up = uin[q];
#pragma unroll
                for (int r = 0; r < 6; ++r) {
                    float lf = vleft[r];
                    float mx = fmaxf(dg, fmaxf(up, lf));
                    float v = sc[r][q] + mx + __logf(__expf(dg - mx) + __expf(up - mx) + __expf(lf - mx));
                    dg = lf;                          // diag for row r+1
                    up = v;                           // up for row r+1
                    vleft[r] = v;
                    vout[r][q] = v;
                }
            }
            bprev = bcarry[3];
#pragma unroll
            for (int q = 0; q < 4; ++q) bcarry[q] = vout[5][q];
#pragma unroll
            for (int r = 0; r < 6; ++r) {
                float4 t;
                t.x = vout[r][0]; t.y = vout[r][1]; t.z = vout[r][2]; t.w = vout[r][3];
                *(float4*)(pV + Tb * 1536 + r * 256) = t;
            }
        }
    };

    float4 buf0[6], buf1[6], buf2[6];
#pragma unroll
    for (int r = 0; r < 6; ++r) {
        buf0[r] = *(const float4*)(pS + 0 * 1536 + r * 256);
        buf1[r] = *(const float4*)(pS + 1 * 1536 + r * 256);
        buf2[r] = *(const float4*)(pS + 2 * 1536 + r * 256);
    }
#pragma unroll 1
    for (int Tb = 0; Tb < 159; Tb += 3) {
        body(buf0, Tb);
        body(buf1, Tb + 1);
        body(buf2, Tb + 2);
    }
}

// ---------------- NW backward: 6 rows/lane, single pass, diag layout, 2x-unrolled pipeline ----------------
// E[i,j] = [i==li && j==lj] + E[i+1,j+1]*exp(V[i,j]-U[i+1,j+1]) + E[i+1,j]*exp(V[i,j]-U[i+1,j])
//        + E[i,j+1]*exp(V[i,j]-U[i,j+1]),   U[i,j] = V[i,j] - sim0[i-1][j-1].
// Lane l owns rows 6l+1..6l+6, sweeping col tiles right-to-left; lane l+1 one tile
// ahead. Neighbor row 6l+7 arrives via dpp_down of lane l+1's r=0 carries. Lane 63's
// neighbor is row 385 (out of range) -> guards; NO LDS, NO multi-pass.
// At body T, lane l works tile ct = 158-T-l -> diag d = 158-T lane-invariant: dense.
__global__ __launch_bounds__(64, 1) void nw_bwd_kernel(const float* __restrict__ simD,
                                                       const float* __restrict__ VD,
                                                       const int* __restrict__ shapes,
                                                       float* __restrict__ ED) {
    int b = blockIdx.x;
    int l = threadIdx.x;
    const float* pS = simD + (size_t)b * SZD + l * 4;
    const float* pV = VD   + (size_t)b * SZD + l * 4;
    float*       pE = ED   + (size_t)b * SZD + l * 4;
    int li = min(max(shapes[2 * b + 0], 0), L_);
    int lj = min(max(shapes[2 * b + 1], 0), L_);
    float e[6] = {0.f, 0.f, 0.f, 0.f, 0.f, 0.f};     // E[i, j+1] carries (per own row)
    float u[6] = {0.f, 0.f, 0.f, 0.f, 0.f, 0.f};     // U[i, j+1] carries
    float ecar[4] = {0.f, 0.f, 0.f, 0.f};            // E[6l+1, tile cols] (for lane l-1)
    float ucar[4] = {0.f, 0.f, 0.f, 0.f};            // U[6l+1, tile cols]
    float eprev_s = 0.f, uprev_s = 0.f;              // E/U[6l+1, right-adjacent col]

    auto body = [&](float4* bufV, float4* bufS, int T) {
        float Vq[6][4], Sq[6][4];
#pragma unroll
        for (int r = 0; r < 6; ++r) {
            float4 tv = bufV[r], ts = bufS[r];
            Vq[r][0] = tv.x; Vq[r][1] = tv.y; Vq[r][2] = tv.z; Vq[r][3] = tv.w;
            Sq[r][0] = ts.x; Sq[r][1] = ts.y; Sq[r][2] = ts.z; Sq[r][3] = ts.w;
        }
        int dP = max(158 - T - 2, 0);                 // re-issue this set for T+2
#pragma unroll
        for (int r = 0; r < 6; ++r) {
            bufV[r] = *(const float4*)(pV + dP * 1536 + r * 256);
            bufS[r] = *(const float4*)(pS + dP * 1536 + r * 256);
        }
        // cross-lane (whole-wave): lane l+1 worked this tile at step T-1
        float enbtd_s = dpp_down1(eprev_s);          // E[6l+7, rightmost col + 1]
        float unbtd_s = dpp_down1(uprev_s);          // U[6l+7, rightmost col + 1]
        float enb_c[4], unb_c[4];
#pragma unroll
        for (int q = 0; q < 4; ++q) {
            enb_c[q] = dpp_down1(ecar[q]);           // E[6l+7, c0+q+1]
            unb_c[q] = dpp_down1(ucar[q]);           // U[6l+7, c0+q+1]
        }
        eprev_s = e[0]; uprev_s = u[0];              // snapshot AFTER dpps
        int ct = 158 - T - l;
        if (ct >= 0 && ct <= 95) {
            float Eo[6][4];
#pragma unroll
            for (int qq = 0; qq < 4; ++qq) {
                const int q = 3 - qq;                // descending cols
                int j = 4 * ct + q + 1;
                bool jlt = (j < L_);
                float eo[6], uo[6];
#pragma unroll
                for (int r = 0; r < 6; ++r) { eo[r] = e[r]; uo[r] = u[r]; }
#pragma unroll
                for (int rr = 0; rr < 6; ++rr) {
                    const int r = 5 - rr;            // descending rows (r+1 fresh first)
                    int i = 6 * l + r + 1;
                    bool ilt = (i < L_);             // false only for l=63, r=5
                    float Vv = Vq[r][q];
                    float u_new = Vv - Sq[r][q];     // U[i, j]
                    float eb_old, ub_old, eb_new, ub_new;
                    if (r == 5) {
                        eb_old = (q == 3) ? enbtd_s : enb_c[q + 1];
                        ub_old = (q == 3) ? unbtd_s : unb_c[q + 1];
                        eb_new = enb_c[q];
                        ub_new = unb_c[q];
                    } else {
                        eb_old = eo[r + 1]; ub_old = uo[r + 1];   // col j+1
                        eb_new = e[r + 1];  ub_new = u[r + 1];    // col j (fresh)
                    }
                    float wtd = (ilt && jlt) ? __expf(Vv - ub_old) : 0.f;
                    float wtu = ilt ? __expf(Vv - ub_new) : 0.f;
                    float wtl = jlt ? __expf(Vv - uo[r]) : 0.f;
                    float en = (i == li && j == lj) ? 1.f : 0.f;
                    en += wtd * eb_old + wtu * eb_new + wtl * eo[r];
                    e[r] = en; u[r] = u_new;
                    Eo[r][q] = en;
                }
            }
#pragma unroll
            for (int q = 0; q < 4; ++q) {            // carries for lane l-1's dpp
                ecar[q] = Eo[0][q];
                ucar[q] = Vq[0][q] - Sq[0][q];
            }
            float* pEd = pE + (size_t)(158 - T) * 1536;
#pragma unroll
            for (int r = 0; r < 6; ++r) {
                float4 t;
                t.x = Eo[r][0]; t.y = Eo[r][1]; t.z = Eo[r][2]; t.w = Eo[r][3];
                *(float4*)(pEd + r * 256) = t;
            }
        }
    };

    float4 bufVA[6], bufSA[6], bufVB[6], bufSB[6];
#pragma unroll
    for (int r = 0; r < 6; ++r) {
        bufVA[r] = *(const float4*)(pV + 158 * 1536 + r * 256);
        bufSA[r] = *(const float4*)(pS + 158 * 1536 + r * 256);
        bufVB[r] = *(const float4*)(pV + 157 * 1536 + r * 256);
        bufSB[r] = *(const float4*)(pS + 157 * 1536 + r * 256);
    }
#pragma unroll 1
    for (int T = 0; T < 160; T += 2) {               // T=159 body: all lanes inactive
        body(bufVA, bufSA, T);
        body(bufVB, bufSB, T + 1);
    }
}

// ---------------- consensus[j,a] = (1/B) sum_n sum_i matrices[n,a,i]*align[n,i,j] ----------------
__global__ __launch_bounds__(256) void consensus_kernel(const float* __restrict__ x,      // (B,A,L)
                                                        const float* __restrict__ ED,     // diag layout
                                                        float* __restrict__ cons) {       // (L,A)
    int n  = blockIdx.y;
    int j0 = blockIdx.x * 64;
    __shared__ float ms[A_][L_];    // 39.9 KB: matrices[n] staged
    for (int idx = threadIdx.x; idx < A_ * L_; idx += 256)
        ((float*)ms)[idx] = x[(size_t)n * A_ * L_ + idx];
    __syncthreads();
    int jl = threadIdx.x & 63;
    int g  = threadIdx.x >> 6;      // 0..3
    int a0 = g * 7;                 // 0,7,14,21
    int na = (a0 + 7 <= A_) ? 7 : (A_ - a0);   // 7,7,7,5
    int j  = j0 + jl;
    float acc[7] = {0.f, 0.f, 0.f, 0.f, 0.f, 0.f, 0.f};
    // E element (row i, col j): (i/6 + j/4)*1536 + (i%6)*256 + (i/6)*4 + (j&3)
    const float* aB = ED + (size_t)n * SZD + (j >> 2) * 1536 + (j & 3);
#pragma unroll 1
    for (int dl = 0; dl < 64; ++dl) {
        const float* ap = aB + dl * 1540;   // dl*1536 + dl*4
#pragma unroll
        for (int dr = 0; dr < 6; ++dr) {
            float al = ap[dr * 256];
            int i = dl * 6 + dr;
#pragma unroll
            for (int t = 0; t < 7; ++t)
                if (t < na) acc[t] = fmaf(al, ms[a0 + t][i], acc[t]);
        }
    }
    for (int t = 0; t < na; ++t)
        atomicAdd(&cons[(size_t)j * A_ + a0 + t], acc[t] * (1.0f / B_));
}

// ---------------- out[n,i,a] = sum_j cons[j,a] * align[n,i,j] ----------------
__global__ __launch_bounds__(256) void out_kernel(const float* __restrict__ ED,  // diag layout
                                                  const float* __restrict__ cons,
                                                  float* __restrict__ out) {
    int n  = blockIdx.y;
    int i0 = blockIdx.x * 32;
    __shared__ float cs[L_][A_];        // 40.0 KB
    __shared__ float as_[32][L_ + 1];   // 49.3 KB (pad: break 384-stride bank alias)
    for (int idx = threadIdx.x; idx < L_ * A_; idx += 256)
        ((float*)cs)[idx] = cons[idx];
    const float* aB = ED + (size_t)n * SZD;
    for (int idx = threadIdx.x; idx < 32 * L_; idx += 256) {
        int r = idx / L_, c = idx - r * L_;
        int z = i0 + r;
        int dl = z / 6, dr = z - dl * 6;
        as_[r][c] = aB[(size_t)(dl + (c >> 2)) * 1536 + dr * 256 + dl * 4 + (c & 3)];
    }
    __syncthreads();
    for (int o = threadIdx.x; o < 32 * A_; o += 256) {
        int il = o / A_, a = o % A_;
        float s = 0.f;
        for (int jj = 0; jj < L_; ++jj)
            s = fmaf(as_[il][jj], cs[jj][a], s);
        out[((size_t)n * L_ + i0 + il) * A_ + a] = s;
    }
}

extern "C" void kernel_launch(void* const* d_in, const int* in_sizes, int n_in,
                              void* d_out, int out_size, void* d_ws, size_t ws_size,
                              hipStream_t stream) {
    const float* matrices = (const float*)d_in[0];   // (B,A,L) f32
    const int*   shapes   = (const int*)d_in[1];     // (B,2) i32
    const float* conv_w   = (const float*)d_in[2];   // (D,A,K) f32
    const float* conv_b   = (const float*)d_in[3];   // (D,) f32
    float* out = (float*)d_out;                      // (B,L,A) f32

    char* p = (char*)d_ws;
    // ED (62.9 MB) aliases ehi+elo (50.3 MB): ehi/elo are dead before nw_bwd runs.
    float*    ED  = (float*)p;
    ushort_t* ehi = (ushort_t*)p;
    ushort_t* elo = ehi + (size_t)B_ * L_ * D_;
    float* simD = (float*)(p + (size_t)B_ * SZD * 4);               // 62.9 MB
    float* VD   = simD + (size_t)B_ * SZD;                          // 62.9 MB
    float* wt   = VD + (size_t)B_ * SZD;                            //  1.0 MB
    float* cons = wt + (size_t)A_ * K_ * D_;                        // 40 KB

    transpose_w_kernel<<<(A_ * K_ * D_ + 255) / 256, 256, 0, stream>>>(conv_w, wt);
    conv_kernel<<<dim3(L_ / 32, B_), 512, 0, stream>>>(matrices, wt, conv_b, ehi, elo);
    sim_kernel<<<dim3(L_ / 64, L_ / 64, B_), 256, 0, stream>>>(ehi, elo, simD);
    nw_fwd_kernel<<<B_, 64, 0, stream>>>(simD, VD);
    nw_bwd_kernel<<<B_, 64, 0, stream>>>(simD, VD, shapes, ED);
    hipMemsetAsync(cons, 0, (size_t)L_ * A_ * sizeof(float), stream);
    consensus_kernel<<<dim3(L_ / 64, B_), 256, 0, stream>>>(matrices, ED, cons);
    out_kernel<<<dim3(L_ / 32, B_), 256, 0, stream>>>(ED, cons, out);
}

// Round 13
// 988.554 us; speedup vs baseline: 1.1336x; 1.0023x over previous
//
#include <hip/hip_runtime.h>
#include <hip/hip_bf16.h>
#include <math.h>

#define B_  64
#define A_  26
#define L_  384
#define D_  512
#define K_  18
#define SZD 245760   // per-batch diagonal-layout stride: 160 diags x 1536 floats

typedef __attribute__((ext_vector_type(8))) short bf16x8;   // 8 bf16 = 4 VGPRs
typedef __attribute__((ext_vector_type(4))) float f32x4;
typedef unsigned short ushort_t;
typedef unsigned int uint_t;

// Diagonal layout: element (row z, col c), l=z/6, r=z%6, ct=c/4:
//   addr = (l+ct)*1536 + r*256 + l*4 + (c&3);  d=l+ct lane-invariant per body -> dense.
__device__ __forceinline__ void stD(float* sp, int z, int c, float v) {
    int dl = z / 6, dr = z - dl * 6;
    sp[(size_t)(dl + (c >> 2)) * 1536 + dr * 256 + dl * 4 + (c & 3)] = v;
}

// RNE f32 -> bf16 bits
__device__ __forceinline__ ushort_t f2bf(float v) {
    uint_t u = __float_as_uint(v);
    uint_t r = (u + 0x7FFFu + ((u >> 16) & 1u)) >> 16;
    return (ushort_t)r;
}

// ---------------- conv weight transpose: (D,A,K) -> (A*K, D) ----------------
__global__ void transpose_w_kernel(const float* __restrict__ w, float* __restrict__ wt) {
    int o = blockIdx.x * blockDim.x + threadIdx.x;   // o = r*D + d
    int total = A_ * K_ * D_;
    if (o >= total) return;
    int d = o % D_;
    int r = o / D_;                                   // r = a*K + k
    wt[o] = w[(size_t)d * (A_ * K_) + r];
}

// ---------------- conv1d -> e_hi/e_lo (B, L, D) bf16 split ----------------
__global__ __launch_bounds__(512) void conv_kernel(const float* __restrict__ x,     // (B, A, L)
                                                   const float* __restrict__ wt,    // (A*K, D)
                                                   const float* __restrict__ bias,  // (D,)
                                                   ushort_t* __restrict__ ehi,      // (B, L, D) bf16
                                                   ushort_t* __restrict__ elo) {    // (B, L, D) bf16
    const int TL = 32;
    const int XW = TL + K_ - 1;     // 49
    int l0 = blockIdx.x * TL;
    int b  = blockIdx.y;
    int d  = threadIdx.x;           // 512 threads, one per output channel
    __shared__ float xs[A_][XW];
    for (int idx = threadIdx.x; idx < A_ * XW; idx += 512) {
        int a = idx / XW, p = idx % XW;
        int g = l0 - (K_ - 1) / 2 + p;  // l0 - 8 + p
        xs[a][p] = (g >= 0 && g < L_) ? x[((size_t)b * A_ + a) * L_ + g] : 0.0f;
    }
    __syncthreads();
    float acc[TL];
#pragma unroll
    for (int l = 0; l < TL; ++l) acc[l] = 0.0f;
#pragma unroll 1
    for (int a = 0; a < A_; ++a) {
        float xr[XW];
#pragma unroll
        for (int p = 0; p < XW; ++p) xr[p] = xs[a][p];
        const float* wrow = wt + (size_t)(a * K_) * D_ + d;
#pragma unroll
        for (int k = 0; k < K_; ++k) {
            float w = wrow[(size_t)k * D_];
#pragma unroll
            for (int l = 0; l < TL; ++l)
                acc[l] = fmaf(xr[k + l], w, acc[l]);
        }
    }
    float bv = bias[d];
#pragma unroll
    for (int l = 0; l < TL; ++l) {
        float v = acc[l] + bv;
        ushort_t h = f2bf(v);
        float hf = __uint_as_float(((uint_t)h) << 16);
        ushort_t lo = f2bf(v - hf);
        size_t idx = ((size_t)b * L_ + (l0 + l)) * D_ + d;
        ehi[idx] = h;
        elo[idx] = lo;
    }
}

// ---------------- sim = E_b · E_0^T via split-bf16 MFMA; writes diagonal layout ----------------
__global__ __launch_bounds__(256) void sim_kernel(const ushort_t* __restrict__ ehi,
                                                  const ushort_t* __restrict__ elo,
                                                  float* __restrict__ simD) {
    int b = blockIdx.z;
    int w = threadIdx.x >> 6;
    int lane = threadIdx.x & 63;
    int l0 = blockIdx.y * 64 + 32 * (w >> 1);
    int m0 = blockIdx.x * 64 + 32 * (w & 1);
    int r = lane & 15, g = lane >> 4;
    size_t rowA = ((size_t)b * L_ + l0 + r) * D_ + g * 8;
    size_t rowB = ((size_t)m0 + r) * D_ + g * 8;      // batch 0
    const ushort_t* pah = ehi + rowA;
    const ushort_t* pal = elo + rowA;
    const ushort_t* pbh = ehi + rowB;
    const ushort_t* pbl = elo + rowB;
    f32x4 acc00 = {0.f, 0.f, 0.f, 0.f}, acc01 = acc00, acc10 = acc00, acc11 = acc00;
#pragma unroll 2
    for (int ks = 0; ks < 16; ++ks) {
        int off = ks * 32;
        bf16x8 Ah0 = *(const bf16x8*)(pah + off);
        bf16x8 Ah1 = *(const bf16x8*)(pah + 16 * D_ + off);
        bf16x8 Al0 = *(const bf16x8*)(pal + off);
        bf16x8 Al1 = *(const bf16x8*)(pal + 16 * D_ + off);
        bf16x8 Bh0 = *(const bf16x8*)(pbh + off);
        bf16x8 Bh1 = *(const bf16x8*)(pbh + 16 * D_ + off);
        bf16x8 Bl0 = *(const bf16x8*)(pbl + off);
        bf16x8 Bl1 = *(const bf16x8*)(pbl + 16 * D_ + off);
        acc00 = __builtin_amdgcn_mfma_f32_16x16x32_bf16(Ah0, Bh0, acc00, 0, 0, 0);
        acc00 = __builtin_amdgcn_mfma_f32_16x16x32_bf16(Ah0, Bl0, acc00, 0, 0, 0);
        acc00 = __builtin_amdgcn_mfma_f32_16x16x32_bf16(Al0, Bh0, acc00, 0, 0, 0);
        acc01 = __builtin_amdgcn_mfma_f32_16x16x32_bf16(Ah0, Bh1, acc01, 0, 0, 0);
        acc01 = __builtin_amdgcn_mfma_f32_16x16x32_bf16(Ah0, Bl1, acc01, 0, 0, 0);
        acc01 = __builtin_amdgcn_mfma_f32_16x16x32_bf16(Al0, Bh1, acc01, 0, 0, 0);
        acc10 = __builtin_amdgcn_mfma_f32_16x16x32_bf16(Ah1, Bh0, acc10, 0, 0, 0);
        acc10 = __builtin_amdgcn_mfma_f32_16x16x32_bf16(Ah1, Bl0, acc10, 0, 0, 0);
        acc10 = __builtin_amdgcn_mfma_f32_16x16x32_bf16(Al1, Bh0, acc10, 0, 0, 0);
        acc11 = __builtin_amdgcn_mfma_f32_16x16x32_bf16(Ah1, Bh1, acc11, 0, 0, 0);
        acc11 = __builtin_amdgcn_mfma_f32_16x16x32_bf16(Ah1, Bl1, acc11, 0, 0, 0);
        acc11 = __builtin_amdgcn_mfma_f32_16x16x32_bf16(Al1, Bh1, acc11, 0, 0, 0);
    }
    float* sp = simD + (size_t)b * SZD;
#pragma unroll
    for (int v = 0; v < 4; ++v) {
        int ar0 = l0 + g * 4 + v, ar1 = ar0 + 16;
        int ac0 = m0 + r,         ac1 = ac0 + 16;
        stD(sp, ar0, ac0, acc00[v]);
        stD(sp, ar0, ac1, acc01[v]);
        stD(sp, ar1, ac0, acc10[v]);
        stD(sp, ar1, ac1, acc11[v]);
    }
}

// ---------------- NW forward: 4-wave round-robin body pipeline, mailbox handoff ----------------
// V[i,j] = sim[i-1,j-1] + smoothmax3(V[i-1,j-1], V[i-1,j], V[i,j-1])   (g=0, t=1)
// Wave w runs bodies T = w, w+4, ... Cross-body state flows via a 4-slot LDS mailbox:
//   MA[l] = vleft[0..3] (self), MB4[l] = {vleft4, vleft5, bprev, -} , MC[l] = bcarry[0..3]
// Consumer lane l reads self at l (vleft, old bcarry[3] for bprev chain) and neighbor
// values at l-1 (bcarry -> up inputs, bprev -> diag input); lane 0 gets zeros (V[0,*]=0).
__global__ __launch_bounds__(256, 1) void nw_fwd_kernel(const float* __restrict__ simD, float* __restrict__ VD) {
    int b = blockIdx.x;
    int tid = threadIdx.x;
    int w = tid >> 6, l = tid & 63;
    __shared__ float4 MA[4][64], MB4[4][64], MC[4][64];
    __shared__ int FL[4];
    const float4 Z4 = {0.f, 0.f, 0.f, 0.f};
    for (int k = tid; k < 256; k += 256) {
        int s = k >> 6, ll = k & 63;
        MA[s][ll] = Z4; MB4[s][ll] = Z4; MC[s][ll] = Z4;
    }
    if (tid < 4) FL[tid] = (tid == 3) ? -1 : -1000000;
    __syncthreads();
    volatile int* flg = FL;
    const float* pS = simD + (size_t)b * SZD + l * 4;
    float*       pV = VD   + (size_t)b * SZD + l * 4;
    float4 buf[6];
#pragma unroll
    for (int r = 0; r < 6; ++r) buf[r] = *(const float4*)(pS + w * 1536 + r * 256);
    int lm = (l == 0) ? 0 : (l - 1);
#pragma unroll 1
    for (int T = w; T < 159; T += 4) {
        int sp = (T - 1) & 3;
        while (flg[sp] != T - 1) {}
        asm volatile("" ::: "memory");
        float4 Ar = MA[sp][l];
        float4 Bs = MB4[sp][l];
        float4 Cs = MC[sp][l];
        float4 Bn = MB4[sp][lm];
        float4 Cn = MC[sp][lm];
        if (l == 0) { Bn = Z4; Cn = Z4; }
        float vleft[6] = {Ar.x, Ar.y, Ar.z, Ar.w, Bs.x, Bs.y};
        float d0 = Bn.z;                              // V[6l, c0]
        float uin[4] = {Cn.x, Cn.y, Cn.z, Cn.w};      // V[6l, c0+q+1]
        float sc[6][4];
#pragma unroll
        for (int r = 0; r < 6; ++r) {
            sc[r][0] = buf[r].x; sc[r][1] = buf[r].y; sc[r][2] = buf[r].z; sc[r][3] = buf[r].w;
        }
        int dP = min(T + 4, 158);                     // next body's tile
#pragma unroll
        for (int r = 0; r < 6; ++r) buf[r] = *(const float4*)(pS + dP * 1536 + r * 256);
        int ct = T - l;
        float nbc[4] = {0.f, 0.f, 0.f, 0.f}, nbp = 0.f;
        if (ct >= 0 && ct <= 95) {
            float vout[6][4];
#pragma unroll
            for (int q = 0; q < 4; ++q) {
                float dg = (q == 0) ? d0 : uin[q - 1];
                float up = uin[q];
#pragma unroll
                for (int r = 0; r < 6; ++r) {
                    float lf = vleft[r];
                    float mx = fmaxf(dg, fmaxf(up, lf));
                    float v = sc[r][q] + mx + __logf(__expf(dg - mx) + __expf(up - mx) + __expf(lf - mx));
                    dg = lf; up = v;
                    vleft[r] = v;
                    vout[r][q] = v;
                }
            }
            nbp = Cs.w;                               // own old bcarry[3] = V[6l+6, 4ct]
#pragma unroll
            for (int q = 0; q < 4; ++q) nbc[q] = vout[5][q];
            float* pVd = pV + (size_t)T * 1536;
#pragma unroll
            for (int r = 0; r < 6; ++r) {
                float4 t;
                t.x = vout[r][0]; t.y = vout[r][1]; t.z = vout[r][2]; t.w = vout[r][3];
                *(float4*)(pVd + r * 256) = t;
            }
        }
        float4 pa; pa.x = vleft[0]; pa.y = vleft[1]; pa.z = vleft[2]; pa.w = vleft[3];
        float4 pb; pb.x = vleft[4]; pb.y = vleft[5]; pb.z = nbp; pb.w = 0.f;
        float4 pc; pc.x = nbc[0]; pc.y = nbc[1]; pc.z = nbc[2]; pc.w = nbc[3];
        MA[w][l] = pa; MB4[w][l] = pb; MC[w][l] = pc;
        asm volatile("s_waitcnt lgkmcnt(0)" ::: "memory");
        if (l == 0) flg[w] = T;
    }
}

// ---------------- NW backward: 4-wave round-robin body pipeline, mailbox handoff ----------------
// E[i,j] = [i==li && j==lj] + E[i+1,j+1]*exp(V[i,j]-U[i+1,j+1]) + E[i+1,j]*exp(V[i,j]-U[i+1,j])
//        + E[i,j+1]*exp(V[i,j]-U[i,j+1]),   U[i,j] = V[i,j] - sim0[i-1][j-1].
// Mailbox: MA={e0..3} MB4={e4,e5,u0,u1} MC={u2..5} (self at l);
//          MD=ecar MEx=ucar MF={eprev_s,uprev_s} (read from neighbor l+1; lane63 -> 0).
__global__ __launch_bounds__(256, 1) void nw_bwd_kernel(const float* __restrict__ simD,
                                                        const float* __restrict__ VD,
                                                        const int* __restrict__ shapes,
                                                        float* __restrict__ ED) {
    int b = blockIdx.x;
    int tid = threadIdx.x;
    int w = tid >> 6, l = tid & 63;
    __shared__ float4 MA[4][64], MB4[4][64], MC[4][64], MD[4][64], MEx[4][64], MF[4][64];
    __shared__ int FL[4];
    const float4 Z4 = {0.f, 0.f, 0.f, 0.f};
    for (int k = tid; k < 256; k += 256) {
        int s = k >> 6, ll = k & 63;
        MA[s][ll] = Z4; MB4[s][ll] = Z4; MC[s][ll] = Z4;
        MD[s][ll] = Z4; MEx[s][ll] = Z4; MF[s][ll] = Z4;
    }
    if (tid < 4) FL[tid] = (tid == 3) ? -1 : -1000000;
    __syncthreads();
    volatile int* flg = FL;
    const float* pS = simD + (size_t)b * SZD + l * 4;
    const float* pV = VD   + (size_t)b * SZD + l * 4;
    float*       pE = ED   + (size_t)b * SZD + l * 4;
    int li = min(max(shapes[2 * b + 0], 0), L_);
    int lj = min(max(shapes[2 * b + 1], 0), L_);
    float4 bufV[6], bufS[6];
#pragma unroll
    for (int r = 0; r < 6; ++r) {
        bufV[r] = *(const float4*)(pV + (158 - w) * 1536 + r * 256);
        bufS[r] = *(const float4*)(pS + (158 - w) * 1536 + r * 256);
    }
    int lp = (l == 63) ? 63 : (l + 1);
#pragma unroll 1
    for (int T = w; T < 159; T += 4) {
        int sp = (T - 1) & 3;
        while (flg[sp] != T - 1) {}
        asm volatile("" ::: "memory");
        float4 Ar = MA[sp][l];
        float4 Br = MB4[sp][l];
        float4 Cr = MC[sp][l];
        float4 Dn = MD[sp][lp];
        float4 En = MEx[sp][lp];
        float4 Fn = MF[sp][lp];
        if (l == 63) { Dn = Z4; En = Z4; Fn = Z4; }
        float e[6] = {Ar.x, Ar.y, Ar.z, Ar.w, Br.x, Br.y};
        float u[6] = {Br.z, Br.w, Cr.x, Cr.y, Cr.z, Cr.w};
        float enb_c[4] = {Dn.x, Dn.y, Dn.z, Dn.w};   // E[6l+7, c0+1+q]
        float unb_c[4] = {En.x, En.y, En.z, En.w};   // U[6l+7, c0+1+q]
        float enbtd_s = Fn.x, unbtd_s = Fn.y;        // E/U[6l+7, rightmost+1]
        float e0r = e[0], u0r = u[0];
        float Vq[6][4], Sq[6][4];
#pragma unroll
        for (int r = 0; r < 6; ++r) {
            Vq[r][0] = bufV[r].x; Vq[r][1] = bufV[r].y; Vq[r][2] = bufV[r].z; Vq[r][3] = bufV[r].w;
            Sq[r][0] = bufS[r].x; Sq[r][1] = bufS[r].y; Sq[r][2] = bufS[r].z; Sq[r][3] = bufS[r].w;
        }
        int dP = max(158 - (T + 4), 0);
#pragma unroll
        for (int r = 0; r < 6; ++r) {
            bufV[r] = *(const float4*)(pV + dP * 1536 + r * 256);
            bufS[r] = *(const float4*)(pS + dP * 1536 + r * 256);
        }
        int ct = 158 - T - l;
        float necar[4] = {0.f, 0.f, 0.f, 0.f}, nucar[4] = {0.f, 0.f, 0.f, 0.f};
        if (ct >= 0 && ct <= 95) {
            float Eo[6][4];
#pragma unroll
            for (int qq = 0; qq < 4; ++qq) {
                const int q = 3 - qq;                // descending cols
                int j = 4 * ct + q + 1;
                bool jlt = (j < L_);
                float eo[6], uo[6];
#pragma unroll
                for (int r = 0; r < 6; ++r) { eo[r] = e[r]; uo[r] = u[r]; }
#pragma unroll
                for (int rr = 0; rr < 6; ++rr) {
                    const int r = 5 - rr;            // descending rows
                    int i = 6 * l + r + 1;
                    bool ilt = (i < L_);             // false only l=63, r=5
                    float Vv = Vq[r][q];
                    float u_new = Vv - Sq[r][q];     // U[i, j]
                    float eb_old, ub_old, eb_new, ub_new;
                    if (r == 5) {
                        eb_old = (q == 3) ? enbtd_s : enb_c[q + 1];
                        ub_old = (q == 3) ? unbtd_s : unb_c[q + 1];
                        eb_new = enb_c[q];
                        ub_new = unb_c[q];
                    } else {
                        eb_old = eo[r + 1]; ub_old = uo[r + 1];   // col j+1
                        eb_new = e[r + 1];  ub_new = u[r + 1];    // col j (fresh)
                    }
                    float wtd = (ilt && jlt) ? __expf(Vv - ub_old) : 0.f;
                    float wtu = ilt ? __expf(Vv - ub_new) : 0.f;
                    float wtl = jlt ? __expf(Vv - uo[r]) : 0.f;
                    float en = (i == li && j == lj) ? 1.f : 0.f;
                    en += wtd * eb_old + wtu * eb_new + wtl * eo[r];
                    e[r] = en; u[r] = u_new;
                    Eo[r][q] = en;
                }
            }
#pragma unroll
            for (int q = 0; q < 4; ++q) {
                necar[q] = Eo[0][q];
                nucar[q] = Vq[0][q] - Sq[0][q];
            }
            float* pEd = pE + (size_t)(158 - T) * 1536;
#pragma unroll
            for (int r = 0; r < 6; ++r) {
                float4 t;
                t.x = Eo[r][0]; t.y = Eo[r][1]; t.z = Eo[r][2]; t.w = Eo[r][3];
                *(float4*)(pEd + r * 256) = t;
            }
        }
        float4 pa; pa.x = e[0]; pa.y = e[1]; pa.z = e[2]; pa.w = e[3];
        float4 pb; pb.x = e[4]; pb.y = e[5]; pb.z = u[0]; pb.w = u[1];
        float4 pc; pc.x = u[2]; pc.y = u[3]; pc.z = u[4]; pc.w = u[5];
        float4 pd; pd.x = necar[0]; pd.y = necar[1]; pd.z = necar[2]; pd.w = necar[3];
        float4 pe; pe.x = nucar[0]; pe.y = nucar[1]; pe.z = nucar[2]; pe.w = nucar[3];
        float4 pf; pf.x = e0r; pf.y = u0r; pf.z = 0.f; pf.w = 0.f;
        MA[w][l] = pa; MB4[w][l] = pb; MC[w][l] = pc;
        MD[w][l] = pd; MEx[w][l] = pe; MF[w][l] = pf;
        asm volatile("s_waitcnt lgkmcnt(0)" ::: "memory");
        if (l == 0) flg[w] = T;
    }
}

// ---------------- consensus[j,a] = (1/B) sum_n sum_i matrices[n,a,i]*align[n,i,j] ----------------
__global__ __launch_bounds__(256) void consensus_kernel(const float* __restrict__ x,      // (B,A,L)
                                                        const float* __restrict__ ED,     // diag layout
                                                        float* __restrict__ cons) {       // (L,A)
    int n  = blockIdx.y;
    int j0 = blockIdx.x * 64;
    __shared__ float ms[A_][L_];    // 39.9 KB: matrices[n] staged
    for (int idx = threadIdx.x; idx < A_ * L_; idx += 256)
        ((float*)ms)[idx] = x[(size_t)n * A_ * L_ + idx];
    __syncthreads();
    int jl = threadIdx.x & 63;
    int g  = threadIdx.x >> 6;      // 0..3
    int a0 = g * 7;                 // 0,7,14,21
    int na = (a0 + 7 <= A_) ? 7 : (A_ - a0);   // 7,7,7,5
    int j  = j0 + jl;
    float acc[7] = {0.f, 0.f, 0.f, 0.f, 0.f, 0.f, 0.f};
    // E element (row i, col j): (i/6 + j/4)*1536 + (i%6)*256 + (i/6)*4 + (j&3)
    const float* aB = ED + (size_t)n * SZD + (j >> 2) * 1536 + (j & 3);
#pragma unroll 1
    for (int dl = 0; dl < 64; ++dl) {
        const float* ap = aB + dl * 1540;   // dl*1536 + dl*4
#pragma unroll
        for (int dr = 0; dr < 6; ++dr) {
            float al = ap[dr * 256];
            int i = dl * 6 + dr;
#pragma unroll
            for (int t = 0; t < 7; ++t)
                if (t < na) acc[t] = fmaf(al, ms[a0 + t][i], acc[t]);
        }
    }
    for (int t = 0; t < na; ++t)
        atomicAdd(&cons[(size_t)j * A_ + a0 + t], acc[t] * (1.0f / B_));
}

// ---------------- out[n,i,a] = sum_j cons[j,a] * align[n,i,j] ----------------
__global__ __launch_bounds__(256) void out_kernel(const float* __restrict__ ED,  // diag layout
                                                  const float* __restrict__ cons,
                                                  float* __restrict__ out) {
    int n  = blockIdx.y;
    int i0 = blockIdx.x * 32;
    __shared__ float cs[L_][A_];        // 40.0 KB
    __shared__ float as_[32][L_ + 1];   // 49.3 KB (pad: break 384-stride bank alias)
    for (int idx = threadIdx.x; idx < L_ * A_; idx += 256)
        ((float*)cs)[idx] = cons[idx];
    const float* aB = ED + (size_t)n * SZD;
    for (int idx = threadIdx.x; idx < 32 * L_; idx += 256) {
        int r = idx / L_, c = idx - r * L_;
        int z = i0 + r;
        int dl = z / 6, dr = z - dl * 6;
        as_[r][c] = aB[(size_t)(dl + (c >> 2)) * 1536 + dr * 256 + dl * 4 + (c & 3)];
    }
    __syncthreads();
    for (int o = threadIdx.x; o < 32 * A_; o += 256) {
        int il = o / A_, a = o % A_;
        float s = 0.f;
        for (int jj = 0; jj < L_; ++jj)
            s = fmaf(as_[il][jj], cs[jj][a], s);
        out[((size_t)n * L_ + i0 + il) * A_ + a] = s;
    }
}

extern "C" void kernel_launch(void* const* d_in, const int* in_sizes, int n_in,
                              void* d_out, int out_size, void* d_ws, size_t ws_size,
                              hipStream_t stream) {
    const float* matrices = (const float*)d_in[0];   // (B,A,L) f32
    const int*   shapes   = (const int*)d_in[1];     // (B,2) i32
    const float* conv_w   = (const float*)d_in[2];   // (D,A,K) f32
    const float* conv_b   = (const float*)d_in[3];   // (D,) f32
    float* out = (float*)d_out;                      // (B,L,A) f32

    char* p = (char*)d_ws;
    // ED (62.9 MB) aliases ehi+elo (50.3 MB): ehi/elo are dead before nw_bwd runs.
    float*    ED  = (float*)p;
    ushort_t* ehi = (ushort_t*)p;
    ushort_t* elo = ehi + (size_t)B_ * L_ * D_;
    float* simD = (float*)(p + (size_t)B_ * SZD * 4);               // 62.9 MB
    float* VD   = simD + (size_t)B_ * SZD;                          // 62.9 MB
    float* wt   = VD + (size_t)B_ * SZD;                            //  1.0 MB
    float* cons = wt + (size_t)A_ * K_ * D_;                        // 40 KB

    transpose_w_kernel<<<(A_ * K_ * D_ + 255) / 256, 256, 0, stream>>>(conv_w, wt);
    conv_kernel<<<dim3(L_ / 32, B_), 512, 0, stream>>>(matrices, wt, conv_b, ehi, elo);
    sim_kernel<<<dim3(L_ / 64, L_ / 64, B_), 256, 0, stream>>>(ehi, elo, simD);
    nw_fwd_kernel<<<B_, 256, 0, stream>>>(simD, VD);
    nw_bwd_kernel<<<B_, 256, 0, stream>>>(simD, VD, shapes, ED);
    hipMemsetAsync(cons, 0, (size_t)L_ * A_ * sizeof(float), stream);
    consensus_kernel<<<dim3(L_ / 64, B_), 256, 0, stream>>>(matrices, ED, cons);
    out_kernel<<<dim3(L_ / 32, B_), 256, 0, stream>>>(ED, cons, out);
}